// Round 4
// baseline (799.960 us; speedup 1.0000x reference)
//
#include <hip/hip_runtime.h>
#include <cstdint>
#include <cstddef>

// Problem constants (DAC RVQ VAE bottleneck)
constexpr int T   = 4096;
constexpr int BB  = 16;
constexpr int D   = 128;   // INPUT_DIM
constexpr int CB  = 1024;  // CODEBOOK_SIZE
constexpr int CD  = 8;     // CODEBOOK_DIM
constexpr int NCB = 9;     // N_CODEBOOKS

constexpr int TBLK = 64;   // columns (t positions) per block
constexpr int NTHR = 512;  // 8 waves
constexpr int NW   = 8;
constexpr int ZLS  = 66;   // Zl row stride (bank-conflict pad)

// Output layout (flat f32 concat, reference return order):
//   z_q [16*128*4096] | kl [1] | commit [1] | cbloss [1] | codes [16*9*4096] | latents [16*72*4096]
constexpr size_t OFF_ZQ    = 0;
constexpr size_t OFF_SCAL  = (size_t)BB * D * T;               // 8388608
constexpr size_t OFF_CODES = OFF_SCAL + 3;                     // 8388611
constexpr size_t OFF_LAT   = OFF_CODES + (size_t)BB * NCB * T; // 8978435

// Workspace layout (units: u32/f32), sequential:
//   afr [294912 u32] : search A-frags (codebook 3-term split)
//   h2c [9216 f32]   : -0.5*||cbn||^2 compact (per entry)
//   afw [30720 u32]  : Z-precompute A-frags (Wall 3-term split)
//   CMt [5184 f32]   : CM[j][72][8] = in_w_flat · out_w_j
//   obs [128 f32]    : sum_i out_b[i][.]
//   bef [72 f32]     : beff[row] = in_b[row] - sum_{j<i(row)} in_w[row]·out_b[j]
//   OPt [1179648 f32]: OP[i][e][128] = out_w_i · cb_i[e]
constexpr size_t AFR_U32 = (size_t)NCB * 64 * 2 * 64 * 4;  // 294912
constexpr size_t H2C_F32 = (size_t)NCB * CB;               // 9216
constexpr size_t AFW_U32 = (size_t)2 * 6 * 2 * 5 * 64 * 4; // 30720
constexpr size_t CM_F32  = (size_t)NCB * 72 * 8;           // 5184
constexpr size_t OBS_F32 = 128;
constexpr size_t BEF_F32 = 72;
constexpr size_t OP_F32  = (size_t)NCB * CB * D;           // 1179648

typedef short bf16x8 __attribute__((ext_vector_type(8)));
typedef float f32x4  __attribute__((ext_vector_type(4)));

__device__ __forceinline__ unsigned short f2bf(float f) {
    unsigned u = __float_as_uint(f);
    return (unsigned short)((u + (((u >> 16) & 1u) + 0x7FFFu)) >> 16);  // RNE
}
__device__ __forceinline__ float bf2f(unsigned short b) {
    return __uint_as_float((unsigned)b << 16);
}

// Z-precompute term pairs: (wA term, zB term). Dropped (1,2),(2,1),(2,2) ~2^-27/prod.
constexpr int PAIR_A[6] = {0, 0, 1, 1, 2, 0};
constexpr int PAIR_B[6] = {0, 1, 0, 1, 0, 2};

__device__ __forceinline__ unsigned short splitterm(float xv, int term) {
    unsigned short t0 = f2bf(xv); if (term == 0) return t0;
    float r1 = xv - bf2f(t0);
    unsigned short t1 = f2bf(r1); if (term == 1) return t1;
    float r2 = r1 - bf2f(t1);
    return f2bf(r2);
}

// ---------------------------------------------------------------------------
// Prep (single launch, role by flat id) — identical to round 3 (verified).
// ---------------------------------------------------------------------------
__global__ void prep_kernel(const float* __restrict__ codebook,
                            const float* __restrict__ in_w,
                            const float* __restrict__ in_b,
                            const float* __restrict__ out_w,
                            const float* __restrict__ out_b,
                            unsigned* __restrict__ afr,
                            float* __restrict__ h2c,
                            unsigned* __restrict__ afw,
                            float* __restrict__ CMt,
                            float* __restrict__ obs,
                            float* __restrict__ bef,
                            float* __restrict__ OPt,
                            float* __restrict__ scal) {
    const int gid = blockIdx.x * blockDim.x + threadIdx.x;
    if (gid == 0) { scal[0] = 0.f; scal[1] = 0.f; scal[2] = 0.f; }

    if (gid < NCB * CB) {
        const int e  = gid;
        const int i  = e >> 10;
        const int en = e & 1023;
        const int et = en >> 4;
        const int m  = en & 15;

        float v[CD]; float s2 = 0.f;
#pragma unroll
        for (int j = 0; j < CD; ++j) { v[j] = codebook[(size_t)e * CD + j]; s2 = fmaf(v[j], v[j], s2); }
        float inv = 1.0f / fmaxf(sqrtf(s2), 1e-12f);
        float cn[CD]; float c2 = 0.f;
#pragma unroll
        for (int j = 0; j < CD; ++j) { cn[j] = v[j] * inv; c2 = fmaf(cn[j], cn[j], c2); }
        h2c[e] = -0.5f * c2;  // exact fp32, negated (MFMA C-init)

        unsigned pk[3][4];
#pragma unroll
        for (int w = 0; w < 4; ++w) {
            float x0 = cn[2 * w], x1 = cn[2 * w + 1];
            unsigned short a0 = f2bf(x0); float r0 = x0 - bf2f(a0);
            unsigned short a1 = f2bf(r0); float q0 = r0 - bf2f(a1);
            unsigned short a2 = f2bf(q0);
            unsigned short b0 = f2bf(x1); float r1 = x1 - bf2f(b0);
            unsigned short b1 = f2bf(r1); float q1 = r1 - bf2f(b1);
            unsigned short b2 = f2bf(q1);
            pk[0][w] = (unsigned)a0 | ((unsigned)b0 << 16);
            pk[1][w] = (unsigned)a1 | ((unsigned)b1 << 16);
            pk[2][w] = (unsigned)a2 | ((unsigned)b2 << 16);
        }
        const int At[8] = {0, 1, 2, 0, 1, 0, 2, 1};
#pragma unroll
        for (int kh = 0; kh < 2; ++kh) {
#pragma unroll
            for (int h = 0; h < 4; ++h) {
                int A1 = At[kh * 4 + (h >> 1)];
                int A2 = At[kh * 4 + 2 + (h >> 1)];
                int dw = (h & 1) * 2;
                size_t off = ((((size_t)i * 64 + et) * 2 + kh) * 64 + (h * 16 + m)) * 4;
                afr[off + 0] = pk[A1][dw];
                afr[off + 1] = pk[A1][dw + 1];
                afr[off + 2] = pk[A2][dw];
                afr[off + 3] = pk[A2][dw + 1];
            }
        }
        return;
    }
    if (gid < 2 * NCB * CB) {
        const int e = gid - NCB * CB;
        const int i = e >> 10;
        float cv[CD];
#pragma unroll
        for (int d = 0; d < CD; ++d) cv[d] = codebook[(size_t)e * CD + d];
        const float* ow = out_w + (size_t)i * D * CD;
        float* dst = OPt + (size_t)e * D;
        for (int r = 0; r < D; ++r) {
            float a = 0.f;
#pragma unroll
            for (int d = 0; d < CD; ++d) a = fmaf(ow[r * CD + d], cv[d], a);
            dst[r] = a;
        }
        return;
    }
    if (gid < 2 * NCB * CB + NCB * 72) {
        const int idx = gid - 2 * NCB * CB;
        const int j = idx / 72, r = idx - j * 72;
        const float* wi = in_w + (size_t)r * D;
        const float* ow = out_w + (size_t)j * D * CD;
        float a[CD];
#pragma unroll
        for (int d = 0; d < CD; ++d) a[d] = 0.f;
        for (int k = 0; k < D; ++k) {
            float w = wi[k];
#pragma unroll
            for (int d = 0; d < CD; ++d) a[d] = fmaf(w, ow[k * CD + d], a[d]);
        }
#pragma unroll
        for (int d = 0; d < CD; ++d) CMt[((size_t)j * 72 + r) * CD + d] = a[d];
        return;
    }
    if (gid < 2 * NCB * CB + NCB * 72 + 128) {
        const int r = gid - (2 * NCB * CB + NCB * 72);
        float a = 0.f;
        for (int i = 0; i < NCB; ++i) a += out_b[(size_t)i * D + r];
        obs[r] = a;
        return;
    }
    if (gid < 2 * NCB * CB + NCB * 72 + 128 + 72) {
        const int row = gid - (2 * NCB * CB + NCB * 72 + 128);
        const int ic  = row >> 3;
        const float* wi = in_w + (size_t)row * D;
        float a = in_b[row];
        for (int j = 0; j < ic; ++j) {
            const float* ob = out_b + (size_t)j * D;
            float s = 0.f;
            for (int k = 0; k < D; ++k) s = fmaf(wi[k], ob[k], s);
            a -= s;
        }
        bef[row] = a;
        return;
    }
    if (gid < 2 * NCB * CB + NCB * 72 + 128 + 72 + 7680) {
        int idx = gid - (2 * NCB * CB + NCB * 72 + 128 + 72);
        const int lane = idx & 63; idx >>= 6;
        const int mt = idx % 5; idx /= 5;
        const int kq = idx & 1; idx >>= 1;
        const int p  = idx % 6;
        const int P  = idx / 6;
        const int h  = lane >> 4, m = lane & 15;
        const int row = mt * 16 + m;
        const int term = PAIR_A[p];
        const int D0 = P * 64 + kq * 32 + h * 4;
        const int doff[4][2] = {{0, 1}, {2, 3}, {16, 17}, {18, 19}};
        unsigned wv[4];
#pragma unroll
        for (int w = 0; w < 4; ++w) {
            unsigned short lo = 0, hi = 0;
            if (row < 72) {
                lo = splitterm(in_w[(size_t)row * D + D0 + doff[w][0]], term);
                hi = splitterm(in_w[(size_t)row * D + D0 + doff[w][1]], term);
            }
            wv[w] = (unsigned)lo | ((unsigned)hi << 16);
        }
        *reinterpret_cast<uint4*>(afw + ((size_t)(((P * 6 + p) * 2 + kq) * 5 + mt) * 64 + lane) * 4)
            = make_uint4(wv[0], wv[1], wv[2], wv[3]);
        return;
    }
}

// ---------------------------------------------------------------------------
// Main fused kernel — 8 waves per block (occupancy: 4 blk/CU x 8 = 32 waves/CU).
// Same math as round 3; per-wave ownership remapped 4 -> 8 waves.
// ---------------------------------------------------------------------------
__global__ __launch_bounds__(NTHR, 8)
void rvq_kernel(const float* __restrict__ x,
                const float* __restrict__ noise,
                const float* __restrict__ codebook,
                const unsigned* __restrict__ afr,
                const float* __restrict__ h2c,
                const unsigned* __restrict__ afw,
                const float* __restrict__ CMt,
                const float* __restrict__ obs,
                const float* __restrict__ bef,
                const float* __restrict__ OPt,
                float* __restrict__ o_zq,
                float* __restrict__ o_scal,
                float* __restrict__ o_codes,
                float* __restrict__ o_lat) {
    __shared__ char     zbuf[24576];        // union: zs (24KB) then Zl (80x66 f32, 21.1KB)
    __shared__ unsigned es[TBLK * 12];      // split en: [col][3 terms][4xu32] (3 KB)
    __shared__ float    redS[NW * TBLK];    // per-wave best score (2 KB)
    __shared__ int      redI[NW * TBLK];    // per-wave best index (2 KB)
    __shared__ int      cidx[NCB * TBLK];   // selected codes (2.25 KB)
    __shared__ float    redw[2 * NW];

    uint2* zs = reinterpret_cast<uint2*>(zbuf);   // [(term*16+slot)*64 + col]
    float* Zl = reinterpret_cast<float*>(zbuf);   // [row*ZLS + col]

    const int tid = threadIdx.x;
    const int c   = tid & 63;            // column for col-parallel phases
    const int s   = tid >> 6;            // wave id (0..7)
    const int su  = __builtin_amdgcn_readfirstlane(s);
    const int b   = blockIdx.x >> 6;
    const int t0  = (blockIdx.x & 63) << 6;
    const int t   = t0 + c;

    const int l  = tid & 63;             // lane
    const int h  = l >> 4;               // 16-lane group
    const int nl = l & 15;               // position-within-tile

    // ================= Phase Z: Z = Wall * z + beff (MFMA) =================
    // Consume mapping: waves 0-3 -> N-tile su, mt 0..2; waves 4-7 -> N-tile su-4, mt 3..4.
    const int mtbase = (su < 4) ? 0 : 3;
    const int nmt    = (su < 4) ? 3 : 2;
    float kl_local = 0.f;
    f32x4 acc[3];
#pragma unroll
    for (int q = 0; q < 3; ++q) {
        int row0 = (mtbase + q) * 16 + h * 4;
        if (q < nmt && row0 < 72) acc[q] = *reinterpret_cast<const f32x4*>(bef + row0);
        else                      acc[q] = f32x4{0.f, 0.f, 0.f, 0.f};
    }

#pragma unroll 1
    for (int P = 0; P < 2; ++P) {
        // ---- produce: rows P*64 + su*8 .. +7, col c ----
        {
            const int r0 = P * 64 + su * 8;
            const float* xm = x     + (size_t)b * 2 * D * T + (size_t)r0 * T + t;
            const float* xs = xm    + (size_t)D * T;
            const float* nz = noise + (size_t)b * D * T     + (size_t)r0 * T + t;
            float zrow[8];
#pragma unroll
            for (int k = 0; k < 8; ++k) {
                float m  = xm[(size_t)k * T];
                float sc = xs[(size_t)k * T];
                float nv = nz[(size_t)k * T];
                float sp  = fmaxf(sc, 0.f) + log1pf(expf(-fabsf(sc)));  // softplus
                float sd  = sp + 1e-4f;
                float var = sd * sd;
                zrow[k]   = fmaf(nv, sd, m);
                kl_local += m * m + var - logf(var) - 1.0f;
            }
#pragma unroll
            for (int db = 0; db < 2; ++db) {
                unsigned w[3][2];
#pragma unroll
                for (int half = 0; half < 2; ++half) {
                    float x0 = zrow[db * 4 + half * 2], x1 = zrow[db * 4 + half * 2 + 1];
                    unsigned short a0 = f2bf(x0); float r1 = x0 - bf2f(a0);
                    unsigned short a1 = f2bf(r1); float r2 = r1 - bf2f(a1);
                    unsigned short a2 = f2bf(r2);
                    unsigned short b0 = f2bf(x1); float s1v = x1 - bf2f(b0);
                    unsigned short b1 = f2bf(s1v); float s2v = s1v - bf2f(b1);
                    unsigned short b2 = f2bf(s2v);
                    w[0][half] = (unsigned)a0 | ((unsigned)b0 << 16);
                    w[1][half] = (unsigned)a1 | ((unsigned)b1 << 16);
                    w[2][half] = (unsigned)a2 | ((unsigned)b2 << 16);
                }
#pragma unroll
                for (int tt = 0; tt < 3; ++tt)
                    zs[(tt * 16 + su * 2 + db) * 64 + c] = make_uint2(w[tt][0], w[tt][1]);
            }
        }
        __syncthreads();
        // ---- consume: wave su -> N-tile (su&3), mt range [mtbase, mtbase+nmt) ----
        {
            const int colB = (su & 3) * 16 + nl;
#pragma unroll
            for (int p = 0; p < 6; ++p) {
#pragma unroll
                for (int kq = 0; kq < 2; ++kq) {
                    uint2 blo = zs[(PAIR_B[p] * 16 + kq * 8 + h) * 64 + colB];
                    uint2 bhi = zs[(PAIR_B[p] * 16 + kq * 8 + 4 + h) * 64 + colB];
                    uint4 bu = make_uint4(blo.x, blo.y, bhi.x, bhi.y);
                    bf16x8 bfr = *reinterpret_cast<bf16x8*>(&bu);
                    const uint4* Aw = reinterpret_cast<const uint4*>(afw)
                                      + (size_t)(((P * 6 + p) * 2 + kq) * 5) * 64 + l;
#pragma unroll
                    for (int q = 0; q < 3; ++q) {
                        if (q < nmt) {
                            uint4 au = Aw[(size_t)(mtbase + q) * 64];
                            bf16x8 af = *reinterpret_cast<bf16x8*>(&au);
                            acc[q] = __builtin_amdgcn_mfma_f32_16x16x32_bf16(af, bfr, acc[q], 0, 0, 0);
                        }
                    }
                }
            }
        }
        __syncthreads();   // zs consumed (pass-1 rewrites / Zl overlays)
    }
    // ---- Zl store (overlays zs; all reads done) ----
#pragma unroll
    for (int q = 0; q < 3; ++q) {
        if (q < nmt) {
#pragma unroll
            for (int r = 0; r < 4; ++r)
                Zl[((mtbase + q) * 16 + h * 4 + r) * ZLS + (su & 3) * 16 + nl] = acc[q][r];
        }
    }

    float loss_local = 0.f;

    // ================= RVQ loop over 9 codebooks ===========================
    for (int i = 0; i < NCB; ++i) {
        __syncthreads();  // Zl rows current (corrections of i-1 done)

        // ---- split phase: normalize z_e, 3-term bf16 split into es --------
        if (tid < 64) {
            float v[CD]; float n2 = 0.f;
#pragma unroll
            for (int j = 0; j < CD; ++j) { v[j] = Zl[(i * CD + j) * ZLS + tid]; n2 = fmaf(v[j], v[j], n2); }
            float inv = 1.0f / fmaxf(sqrtf(n2), 1e-12f);
            unsigned pk[3][4];
#pragma unroll
            for (int w = 0; w < 4; ++w) {
                float x0 = v[2 * w] * inv, x1 = v[2 * w + 1] * inv;
                unsigned short a0 = f2bf(x0); float r0 = x0 - bf2f(a0);
                unsigned short a1 = f2bf(r0); float q0 = r0 - bf2f(a1);
                unsigned short a2 = f2bf(q0);
                unsigned short b0 = f2bf(x1); float r1 = x1 - bf2f(b0);
                unsigned short b1 = f2bf(r1); float q1 = r1 - bf2f(b1);
                unsigned short b2 = f2bf(q1);
                pk[0][w] = (unsigned)a0 | ((unsigned)b0 << 16);
                pk[1][w] = (unsigned)a1 | ((unsigned)b1 << 16);
                pk[2][w] = (unsigned)a2 | ((unsigned)b2 << 16);
            }
            uint4* ep = reinterpret_cast<uint4*>(&es[(size_t)tid * 12]);
            ep[0] = make_uint4(pk[0][0], pk[0][1], pk[0][2], pk[0][3]);
            ep[1] = make_uint4(pk[1][0], pk[1][1], pk[1][2], pk[1][3]);
            ep[2] = make_uint4(pk[2][0], pk[2][1], pk[2][2], pk[2][3]);
        }
        // ---- latents output: wave su writes z_e row su for all 64 cols ----
        {
            float la = Zl[(i * CD + su) * ZLS + c];
            o_lat[(size_t)b * (NCB * CD) * T + (size_t)(i * CD + su) * T + t] = la;
        }
        __syncthreads();

        // ---- build B fragments (en side) from es --------------------------
        bf16x8 bfrag[4][2];
        {
            const int dwo = (h & 1) * 2;
            const int tA  = h >> 1;
            const int tB  = 1 + (h >> 1);
#pragma unroll
            for (int pt = 0; pt < 4; ++pt) {
                const int col = pt * 16 + nl;
                uint2 lo0 = *reinterpret_cast<const uint2*>(&es[col * 12 + 0 * 4 + dwo]);
                uint2 hi0 = *reinterpret_cast<const uint2*>(&es[col * 12 + tA * 4 + dwo]);
                uint2 lh1 = *reinterpret_cast<const uint2*>(&es[col * 12 + tB * 4 + dwo]);
                uint4 t0v = make_uint4(lo0.x, lo0.y, hi0.x, hi0.y);
                uint4 t1v = make_uint4(lh1.x, lh1.y, lh1.x, lh1.y);
                bfrag[pt][0] = *reinterpret_cast<bf16x8*>(&t0v);
                bfrag[pt][1] = *reinterpret_cast<bf16x8*>(&t1v);
            }
        }

        // ---- MFMA search: wave su owns entries [su*128, su*128+128) -------
        float best[4] = {-3.0e38f, -3.0e38f, -3.0e38f, -3.0e38f};
        int   bidx[4] = {0, 0, 0, 0};
        {
            const uint4* Ab = reinterpret_cast<const uint4*>(afr)
                              + ((size_t)(i * 64 + su * 8) * 2) * 64 + l;
            const f32x4* Hb = reinterpret_cast<const f32x4*>(h2c)
                              + (size_t)i * 256 + su * 32;
            int eb = su * 128 + h * 4;   // entry index base for reg 0
#pragma unroll 2
            for (int e8 = 0; e8 < 8; ++e8) {
                uint4 ua0 = Ab[0];     // kh0 A-fragment (16B/lane, coalesced)
                uint4 ua1 = Ab[64];    // kh1 A-fragment
                f32x4 hv  = Hb[e8 * 4 + h];   // exact -h2 as C-init
                bf16x8 a0 = *reinterpret_cast<bf16x8*>(&ua0);
                bf16x8 a1 = *reinterpret_cast<bf16x8*>(&ua1);
#pragma unroll
                for (int pt = 0; pt < 4; ++pt) {
                    f32x4 accd = __builtin_amdgcn_mfma_f32_16x16x32_bf16(a0, bfrag[pt][0], hv, 0, 0, 0);
                    accd = __builtin_amdgcn_mfma_f32_16x16x32_bf16(a1, bfrag[pt][1], accd, 0, 0, 0);
#pragma unroll
                    for (int r = 0; r < 4; ++r) {
                        float sc = accd[r];
                        if (sc > best[pt]) { best[pt] = sc; bidx[pt] = eb + r; }  // strict >: first idx
                    }
                }
                Ab += 128; eb += 16;
            }
        }

        // wave-internal merge (explicit first-index tie-break)
#pragma unroll
        for (int off = 16; off <= 32; off <<= 1) {
#pragma unroll
            for (int pt = 0; pt < 4; ++pt) {
                float ob = __shfl_xor(best[pt], off, 64);
                int   oi = __shfl_xor(bidx[pt], off, 64);
                bool tk = (ob > best[pt]) || (ob == best[pt] && oi < bidx[pt]);
                if (tk) { best[pt] = ob; bidx[pt] = oi; }
            }
        }
        if (l < 16) {
#pragma unroll
            for (int pt = 0; pt < 4; ++pt) {
                redS[su * 64 + pt * 16 + l] = best[pt];
                redI[su * 64 + pt * 16 + l] = bidx[pt];
            }
        }
        __syncthreads();

        // final reduce across 8 waves (ascending wave = ascending entry range)
        float bsc = redS[c];
        int   bi  = redI[c];
#pragma unroll
        for (int ww = 1; ww < NW; ++ww) {
            float v2 = redS[ww * TBLK + c];
            int   vi = redI[ww * TBLK + c];
            if (v2 > bsc) { bsc = v2; bi = vi; }
        }
        cidx[i * TBLK + c] = bi;   // benign multi-write of identical value
        if (s == 0) o_codes[(size_t)b * NCB * T + (size_t)i * T + t] = (float)bi;

        // gather raw codebook row; loss (once per column)
        float cv[CD];
        {
            const float4* cr4 = (const float4*)(codebook + ((size_t)i * CB + bi) * CD);
            float4 qa = cr4[0], qb = cr4[1];
            cv[0] = qa.x; cv[1] = qa.y; cv[2] = qa.z; cv[3] = qa.w;
            cv[4] = qb.x; cv[5] = qb.y; cv[6] = qb.z; cv[7] = qb.w;
            if (s == 0) {
#pragma unroll
                for (int j = 0; j < CD; ++j) {
                    float dd = cv[j] - Zl[(i * CD + j) * ZLS + c];
                    loss_local = fmaf(dd, dd, loss_local);
                }
            }
        }

        // ---- corrections: Z[row] -= CM[i][row] . cv, rows (i+1)*8 .. 71 ---
        {
            const int nf = 64 - 8 * i;
            for (int rr = su; rr < nf; rr += NW) {
                const int row = (i + 1) * 8 + rr;
                float zv = Zl[row * ZLS + c];
                const float* cm = CMt + ((size_t)i * 72 + row) * CD;
#pragma unroll
                for (int d2 = 0; d2 < CD; ++d2) zv = fmaf(-cm[d2], cv[d2], zv);
                Zl[row * ZLS + c] = zv;
            }
        }
    }
    __syncthreads();  // cidx complete

    // ================= final: z_q = obs + sum_i OP[i][code_i] ==============
    {
        f32x4 oa[4];
#pragma unroll
        for (int kb = 0; kb < 4; ++kb)
            oa[kb] = *reinterpret_cast<const f32x4*>(obs + su * 16 + kb * 4);
#pragma unroll
        for (int i2 = 0; i2 < NCB; ++i2) {
            int code = cidx[i2 * TBLK + c];
            const f32x4* op = reinterpret_cast<const f32x4*>(OPt + ((size_t)(i2 * CB + code)) * D + su * 16);
#pragma unroll
            for (int kb = 0; kb < 4; ++kb) oa[kb] += op[kb];
        }
        float* oq = o_zq + (size_t)b * D * T + (size_t)(su * 16) * T + t;
#pragma unroll
        for (int kb = 0; kb < 4; ++kb)
#pragma unroll
            for (int r = 0; r < 4; ++r)
                oq[(size_t)(kb * 4 + r) * T] = oa[kb][r];
    }

    // ================= scalar reductions ===================================
    float v = kl_local;
#pragma unroll
    for (int o = 32; o > 0; o >>= 1) v += __shfl_down(v, o, 64);
    float w2 = loss_local;
#pragma unroll
    for (int o = 32; o > 0; o >>= 1) w2 += __shfl_down(w2, o, 64);
    if ((tid & 63) == 0) { redw[s] = v; redw[NW + s] = w2; }
    __syncthreads();
    if (tid == 0) {
        float ks = 0.f, ls = 0.f;
#pragma unroll
        for (int q = 0; q < NW; ++q) { ks += redw[q]; ls += redw[NW + q]; }
        atomicAdd(&o_scal[0], ks * (1.0f / 65536.0f));               // kl: /(B*T)
        float lsn = ls * (1.0f / (524288.0f * 9.0f));                // /(B*8*T)/NCB
        atomicAdd(&o_scal[1], lsn);                                  // commitment
        atomicAdd(&o_scal[2], lsn);                                  // codebook (identical in eval)
    }
}

extern "C" void kernel_launch(void* const* d_in, const int* in_sizes, int n_in,
                              void* d_out, int out_size, void* d_ws, size_t ws_size,
                              hipStream_t stream) {
    const float* x        = (const float*)d_in[0];
    const float* noise    = (const float*)d_in[1];
    const float* in_w     = (const float*)d_in[2];
    const float* in_b     = (const float*)d_in[3];
    const float* codebook = (const float*)d_in[4];
    const float* out_w    = (const float*)d_in[5];
    const float* out_b    = (const float*)d_in[6];

    float* out     = (float*)d_out;
    float* o_zq    = out + OFF_ZQ;
    float* o_scal  = out + OFF_SCAL;
    float* o_codes = out + OFF_CODES;
    float* o_lat   = out + OFF_LAT;

    unsigned* afr = (unsigned*)d_ws;
    float*    h2c = (float*)(afr + AFR_U32);
    unsigned* afw = (unsigned*)(h2c + H2C_F32);
    float*    CMt = (float*)(afw + AFW_U32);
    float*    obs = CMt + CM_F32;
    float*    bef = obs + OBS_F32;
    float*    OPt = bef + BEF_F32;

    const int prep_total = 2 * NCB * CB + NCB * 72 + 128 + 72 + 7680;  // 26960
    prep_kernel<<<(prep_total + 255) / 256, 256, 0, stream>>>(
        codebook, in_w, in_b, out_w, out_b, afr, h2c, afw, CMt, obs, bef, OPt, o_scal);

    dim3 grid(BB * (T / TBLK));  // 16 * 64 = 1024 blocks
    rvq_kernel<<<grid, NTHR, 0, stream>>>(x, noise, codebook,
                                          afr, h2c, afw, CMt, obs, bef, OPt,
                                          o_zq, o_scal, o_codes, o_lat);
}

// Round 6
// 707.304 us; speedup vs baseline: 1.1310x; 1.1310x over previous
//
#include <hip/hip_runtime.h>
#include <cstdint>
#include <cstddef>

// Problem constants (DAC RVQ VAE bottleneck)
constexpr int T   = 4096;
constexpr int BB  = 16;
constexpr int D   = 128;   // INPUT_DIM
constexpr int CB  = 1024;  // CODEBOOK_SIZE
constexpr int CD  = 8;     // CODEBOOK_DIM
constexpr int NCB = 9;     // N_CODEBOOKS

constexpr int TBLK = 64;   // columns (t positions) per block
constexpr int NTHR = 256;  // 4 waves
constexpr int ZLS  = 66;   // Zl row stride (bank-conflict pad)

// Output layout (flat f32 concat, reference return order):
//   z_q [16*128*4096] | kl [1] | commit [1] | cbloss [1] | codes [16*9*4096] | latents [16*72*4096]
constexpr size_t OFF_ZQ    = 0;
constexpr size_t OFF_SCAL  = (size_t)BB * D * T;               // 8388608
constexpr size_t OFF_CODES = OFF_SCAL + 3;                     // 8388611
constexpr size_t OFF_LAT   = OFF_CODES + (size_t)BB * NCB * T; // 8978435

// Workspace layout (units: u32/f32), sequential:
//   afr [294912 u32] : search A-frags (codebook 3-term split)
//   h2c [9216 f32]   : -0.5*||cbn||^2 compact (per entry)
//   afw [30720 u32]  : Z-precompute A-frags (Wall 3-term split)
//   CMt [5184 f32]   : CM[j][72][8] = in_w_flat · out_w_j
//   obs [128 f32]    : sum_i out_b[i][.]
//   bef [72 f32]     : beff[row] = in_b[row] - sum_{j<i(row)} in_w[row]·out_b[j]
//   OPt [1179648 f32]: OP[i][e][128] = out_w_i · cb_i[e]
constexpr size_t AFR_U32 = (size_t)NCB * 64 * 2 * 64 * 4;  // 294912
constexpr size_t H2C_F32 = (size_t)NCB * CB;               // 9216
constexpr size_t AFW_U32 = (size_t)2 * 6 * 2 * 5 * 64 * 4; // 30720
constexpr size_t CM_F32  = (size_t)NCB * 72 * 8;           // 5184
constexpr size_t OBS_F32 = 128;
constexpr size_t BEF_F32 = 72;
constexpr size_t OP_F32  = (size_t)NCB * CB * D;           // 1179648

typedef short bf16x8 __attribute__((ext_vector_type(8)));
typedef float f32x4  __attribute__((ext_vector_type(4)));

__device__ __forceinline__ unsigned short f2bf(float f) {
    unsigned u = __float_as_uint(f);
    return (unsigned short)((u + (((u >> 16) & 1u) + 0x7FFFu)) >> 16);  // RNE
}
__device__ __forceinline__ float bf2f(unsigned short b) {
    return __uint_as_float((unsigned)b << 16);
}

// Z-precompute term pairs: (wA term, zB term). Dropped (1,2),(2,1),(2,2) ~2^-27/prod.
constexpr int PAIR_A[6] = {0, 0, 1, 1, 2, 0};
constexpr int PAIR_B[6] = {0, 1, 0, 1, 0, 2};

__device__ __forceinline__ unsigned short splitterm(float xv, int term) {
    unsigned short t0 = f2bf(xv); if (term == 0) return t0;
    float r1 = xv - bf2f(t0);
    unsigned short t1 = f2bf(r1); if (term == 1) return t1;
    float r2 = r1 - bf2f(t1);
    return f2bf(r2);
}

// ---------------------------------------------------------------------------
// Prep (single launch, role by flat id) — identical to round 3 (verified).
// ---------------------------------------------------------------------------
__global__ void prep_kernel(const float* __restrict__ codebook,
                            const float* __restrict__ in_w,
                            const float* __restrict__ in_b,
                            const float* __restrict__ out_w,
                            const float* __restrict__ out_b,
                            unsigned* __restrict__ afr,
                            float* __restrict__ h2c,
                            unsigned* __restrict__ afw,
                            float* __restrict__ CMt,
                            float* __restrict__ obs,
                            float* __restrict__ bef,
                            float* __restrict__ OPt,
                            float* __restrict__ scal) {
    const int gid = blockIdx.x * blockDim.x + threadIdx.x;
    if (gid == 0) { scal[0] = 0.f; scal[1] = 0.f; scal[2] = 0.f; }

    if (gid < NCB * CB) {
        const int e  = gid;
        const int i  = e >> 10;
        const int en = e & 1023;
        const int et = en >> 4;
        const int m  = en & 15;

        float v[CD]; float s2 = 0.f;
#pragma unroll
        for (int j = 0; j < CD; ++j) { v[j] = codebook[(size_t)e * CD + j]; s2 = fmaf(v[j], v[j], s2); }
        float inv = 1.0f / fmaxf(sqrtf(s2), 1e-12f);
        float cn[CD]; float c2 = 0.f;
#pragma unroll
        for (int j = 0; j < CD; ++j) { cn[j] = v[j] * inv; c2 = fmaf(cn[j], cn[j], c2); }
        h2c[e] = -0.5f * c2;  // exact fp32, negated (MFMA C-init)

        unsigned pk[3][4];
#pragma unroll
        for (int w = 0; w < 4; ++w) {
            float x0 = cn[2 * w], x1 = cn[2 * w + 1];
            unsigned short a0 = f2bf(x0); float r0 = x0 - bf2f(a0);
            unsigned short a1 = f2bf(r0); float q0 = r0 - bf2f(a1);
            unsigned short a2 = f2bf(q0);
            unsigned short b0 = f2bf(x1); float r1 = x1 - bf2f(b0);
            unsigned short b1 = f2bf(r1); float q1 = r1 - bf2f(b1);
            unsigned short b2 = f2bf(q1);
            pk[0][w] = (unsigned)a0 | ((unsigned)b0 << 16);
            pk[1][w] = (unsigned)a1 | ((unsigned)b1 << 16);
            pk[2][w] = (unsigned)a2 | ((unsigned)b2 << 16);
        }
        const int At[8] = {0, 1, 2, 0, 1, 0, 2, 1};
#pragma unroll
        for (int kh = 0; kh < 2; ++kh) {
#pragma unroll
            for (int h = 0; h < 4; ++h) {
                int A1 = At[kh * 4 + (h >> 1)];
                int A2 = At[kh * 4 + 2 + (h >> 1)];
                int dw = (h & 1) * 2;
                size_t off = ((((size_t)i * 64 + et) * 2 + kh) * 64 + (h * 16 + m)) * 4;
                afr[off + 0] = pk[A1][dw];
                afr[off + 1] = pk[A1][dw + 1];
                afr[off + 2] = pk[A2][dw];
                afr[off + 3] = pk[A2][dw + 1];
            }
        }
        return;
    }
    if (gid < 2 * NCB * CB) {
        const int e = gid - NCB * CB;
        const int i = e >> 10;
        float cv[CD];
#pragma unroll
        for (int d = 0; d < CD; ++d) cv[d] = codebook[(size_t)e * CD + d];
        const float* ow = out_w + (size_t)i * D * CD;
        float* dst = OPt + (size_t)e * D;
        for (int r = 0; r < D; ++r) {
            float a = 0.f;
#pragma unroll
            for (int d = 0; d < CD; ++d) a = fmaf(ow[r * CD + d], cv[d], a);
            dst[r] = a;
        }
        return;
    }
    if (gid < 2 * NCB * CB + NCB * 72) {
        const int idx = gid - 2 * NCB * CB;
        const int j = idx / 72, r = idx - j * 72;
        const float* wi = in_w + (size_t)r * D;
        const float* ow = out_w + (size_t)j * D * CD;
        float a[CD];
#pragma unroll
        for (int d = 0; d < CD; ++d) a[d] = 0.f;
        for (int k = 0; k < D; ++k) {
            float w = wi[k];
#pragma unroll
            for (int d = 0; d < CD; ++d) a[d] = fmaf(w, ow[k * CD + d], a[d]);
        }
#pragma unroll
        for (int d = 0; d < CD; ++d) CMt[((size_t)j * 72 + r) * CD + d] = a[d];
        return;
    }
    if (gid < 2 * NCB * CB + NCB * 72 + 128) {
        const int r = gid - (2 * NCB * CB + NCB * 72);
        float a = 0.f;
        for (int i = 0; i < NCB; ++i) a += out_b[(size_t)i * D + r];
        obs[r] = a;
        return;
    }
    if (gid < 2 * NCB * CB + NCB * 72 + 128 + 72) {
        const int row = gid - (2 * NCB * CB + NCB * 72 + 128);
        const int ic  = row >> 3;
        const float* wi = in_w + (size_t)row * D;
        float a = in_b[row];
        for (int j = 0; j < ic; ++j) {
            const float* ob = out_b + (size_t)j * D;
            float s = 0.f;
            for (int k = 0; k < D; ++k) s = fmaf(wi[k], ob[k], s);
            a -= s;
        }
        bef[row] = a;
        return;
    }
    if (gid < 2 * NCB * CB + NCB * 72 + 128 + 72 + 7680) {
        int idx = gid - (2 * NCB * CB + NCB * 72 + 128 + 72);
        const int lane = idx & 63; idx >>= 6;
        const int mt = idx % 5; idx /= 5;
        const int kq = idx & 1; idx >>= 1;
        const int p  = idx % 6;
        const int P  = idx / 6;
        const int h  = lane >> 4, m = lane & 15;
        const int row = mt * 16 + m;
        const int term = PAIR_A[p];
        const int D0 = P * 64 + kq * 32 + h * 4;
        const int doff[4][2] = {{0, 1}, {2, 3}, {16, 17}, {18, 19}};
        unsigned wv[4];
#pragma unroll
        for (int w = 0; w < 4; ++w) {
            unsigned short lo = 0, hi = 0;
            if (row < 72) {
                lo = splitterm(in_w[(size_t)row * D + D0 + doff[w][0]], term);
                hi = splitterm(in_w[(size_t)row * D + D0 + doff[w][1]], term);
            }
            wv[w] = (unsigned)lo | ((unsigned)hi << 16);
        }
        *reinterpret_cast<uint4*>(afw + ((size_t)(((P * 6 + p) * 2 + kq) * 5 + mt) * 64 + lane) * 4)
            = make_uint4(wv[0], wv[1], wv[2], wv[3]);
        return;
    }
}

// ---------------------------------------------------------------------------
// Main fused kernel — round-3 structure (4 waves/block), LDS repacked to
// 26912 B (6 blocks/CU) + dual-chain argmax for select-ILP.
// LDS map inside zbuf[24576]:
//   phase Z:  zs [48][64] uint2            (full 24576 B)
//   RVQ loop: Zl [72][66] f32  @ +0        (19008 B)
//             redS[4][64] f32  @ +19008    (1024 B)   (Zl rows 72-79 dead zone)
//             redI[4][64] i32  @ +20032    (1024 B)
//             es  [64][12] u32 @ +21504    (3072 B)
// ---------------------------------------------------------------------------
__global__ __launch_bounds__(NTHR, 6)
void rvq_kernel(const float* __restrict__ x,
                const float* __restrict__ noise,
                const float* __restrict__ codebook,
                const unsigned* __restrict__ afr,
                const float* __restrict__ h2c,
                const unsigned* __restrict__ afw,
                const float* __restrict__ CMt,
                const float* __restrict__ obs,
                const float* __restrict__ bef,
                const float* __restrict__ OPt,
                float* __restrict__ o_zq,
                float* __restrict__ o_scal,
                float* __restrict__ o_codes,
                float* __restrict__ o_lat) {
    __shared__ char  zbuf[24576];
    __shared__ int   cidx[NCB * TBLK];   // selected codes (2.25 KB)
    __shared__ float redw[8];

    uint2*    zs   = reinterpret_cast<uint2*>(zbuf);            // [(term*16+slot)*64 + col]
    float*    Zl   = reinterpret_cast<float*>(zbuf);            // [row*ZLS + col], rows 0..71
    float*    redS = reinterpret_cast<float*>(zbuf + 19008);
    int*      redI = reinterpret_cast<int*>(zbuf + 20032);
    unsigned* es   = reinterpret_cast<unsigned*>(zbuf + 21504); // [col][3 terms][4xu32]

    const int tid = threadIdx.x;
    const int c   = tid & 63;            // column for col-parallel phases
    const int s   = tid >> 6;            // wave id
    const int su  = __builtin_amdgcn_readfirstlane(s);
    const int b   = blockIdx.x >> 6;
    const int t0  = (blockIdx.x & 63) << 6;
    const int t   = t0 + c;

    const int l  = tid & 63;             // lane
    const int h  = l >> 4;               // 16-lane group
    const int nl = l & 15;               // position-within-tile

    // ================= Phase Z: Z = Wall * z + beff (MFMA) =================
    float kl_local = 0.f;
    f32x4 acc[5];
#pragma unroll
    for (int mt = 0; mt < 5; ++mt) {
        int row0 = mt * 16 + h * 4;
        if (row0 < 72) acc[mt] = *reinterpret_cast<const f32x4*>(bef + row0);
        else           acc[mt] = f32x4{0.f, 0.f, 0.f, 0.f};
    }

#pragma unroll 1
    for (int P = 0; P < 2; ++P) {
        // ---- produce: rows P*64 + su*16 .. +15, col c ----
        {
            const int r0 = P * 64 + su * 16;
            const float* xm = x     + (size_t)b * 2 * D * T + (size_t)r0 * T + t;
            const float* xs = xm    + (size_t)D * T;
            const float* nz = noise + (size_t)b * D * T     + (size_t)r0 * T + t;
            float zrow[16];
#pragma unroll
            for (int k = 0; k < 16; ++k) {
                float m  = xm[(size_t)k * T];
                float sc = xs[(size_t)k * T];
                float nv = nz[(size_t)k * T];
                float sp  = fmaxf(sc, 0.f) + log1pf(expf(-fabsf(sc)));  // softplus
                float sd  = sp + 1e-4f;
                float var = sd * sd;
                zrow[k]   = fmaf(nv, sd, m);
                kl_local += m * m + var - logf(var) - 1.0f;
            }
#pragma unroll
            for (int db = 0; db < 4; ++db) {
                unsigned w[3][2];
#pragma unroll
                for (int half = 0; half < 2; ++half) {
                    float x0 = zrow[db * 4 + half * 2], x1 = zrow[db * 4 + half * 2 + 1];
                    unsigned short a0 = f2bf(x0); float r1 = x0 - bf2f(a0);
                    unsigned short a1 = f2bf(r1); float r2 = r1 - bf2f(a1);
                    unsigned short a2 = f2bf(r2);
                    unsigned short b0 = f2bf(x1); float s1v = x1 - bf2f(b0);
                    unsigned short b1 = f2bf(s1v); float s2v = s1v - bf2f(b1);
                    unsigned short b2 = f2bf(s2v);
                    w[0][half] = (unsigned)a0 | ((unsigned)b0 << 16);
                    w[1][half] = (unsigned)a1 | ((unsigned)b1 << 16);
                    w[2][half] = (unsigned)a2 | ((unsigned)b2 << 16);
                }
#pragma unroll
                for (int tt = 0; tt < 3; ++tt)
                    zs[(tt * 16 + su * 4 + db) * 64 + c] = make_uint2(w[tt][0], w[tt][1]);
            }
        }
        __syncthreads();
        // ---- consume: wave su = N-tile su (cols su*16+nl) ----
        {
            const int colB = su * 16 + nl;
#pragma unroll
            for (int p = 0; p < 6; ++p) {
#pragma unroll
                for (int kq = 0; kq < 2; ++kq) {
                    uint2 blo = zs[(PAIR_B[p] * 16 + kq * 8 + h) * 64 + colB];
                    uint2 bhi = zs[(PAIR_B[p] * 16 + kq * 8 + 4 + h) * 64 + colB];
                    uint4 bu = make_uint4(blo.x, blo.y, bhi.x, bhi.y);
                    bf16x8 bfr = *reinterpret_cast<bf16x8*>(&bu);
                    const uint4* Aw = reinterpret_cast<const uint4*>(afw)
                                      + (size_t)(((P * 6 + p) * 2 + kq) * 5) * 64 + l;
#pragma unroll
                    for (int mt = 0; mt < 5; ++mt) {
                        uint4 au = Aw[(size_t)mt * 64];
                        bf16x8 af = *reinterpret_cast<bf16x8*>(&au);
                        acc[mt] = __builtin_amdgcn_mfma_f32_16x16x32_bf16(af, bfr, acc[mt], 0, 0, 0);
                    }
                }
            }
        }
        __syncthreads();   // zs consumed (pass-1 rewrites / Zl overlays)
    }
    // ---- Zl store (overlays zs; all reads done). rows < 72 only ----------
#pragma unroll
    for (int mt = 0; mt < 5; ++mt) {
        const int row0 = mt * 16 + h * 4;
        if (row0 < 72) {
#pragma unroll
            for (int r = 0; r < 4; ++r)
                Zl[(row0 + r) * ZLS + su * 16 + nl] = acc[mt][r];
        }
    }

    float loss_local = 0.f;

    // ================= RVQ loop over 9 codebooks ===========================
    for (int i = 0; i < NCB; ++i) {
        __syncthreads();  // Zl rows current (corrections of i-1 done)

        // ---- split phase: normalize z_e, 3-term bf16 split into es --------
        if (tid < 64) {
            float v[CD]; float n2 = 0.f;
#pragma unroll
            for (int j = 0; j < CD; ++j) { v[j] = Zl[(i * CD + j) * ZLS + tid]; n2 = fmaf(v[j], v[j], n2); }
            float inv = 1.0f / fmaxf(sqrtf(n2), 1e-12f);
            unsigned pk[3][4];
#pragma unroll
            for (int w = 0; w < 4; ++w) {
                float x0 = v[2 * w] * inv, x1 = v[2 * w + 1] * inv;
                unsigned short a0 = f2bf(x0); float r0 = x0 - bf2f(a0);
                unsigned short a1 = f2bf(r0); float q0 = r0 - bf2f(a1);
                unsigned short a2 = f2bf(q0);
                unsigned short b0 = f2bf(x1); float r1 = x1 - bf2f(b0);
                unsigned short b1 = f2bf(r1); float q1 = r1 - bf2f(b1);
                unsigned short b2 = f2bf(q1);
                pk[0][w] = (unsigned)a0 | ((unsigned)b0 << 16);
                pk[1][w] = (unsigned)a1 | ((unsigned)b1 << 16);
                pk[2][w] = (unsigned)a2 | ((unsigned)b2 << 16);
            }
            uint4* ep = reinterpret_cast<uint4*>(&es[(size_t)tid * 12]);
            ep[0] = make_uint4(pk[0][0], pk[0][1], pk[0][2], pk[0][3]);
            ep[1] = make_uint4(pk[1][0], pk[1][1], pk[1][2], pk[1][3]);
            ep[2] = make_uint4(pk[2][0], pk[2][1], pk[2][2], pk[2][3]);
        }
        // ---- latents output (z_e rows final for this codebook) -----------
        {
            float la0 = Zl[(i * CD + su) * ZLS + c];
            float la1 = Zl[(i * CD + su + 4) * ZLS + c];
            o_lat[(size_t)b * (NCB * CD) * T + (size_t)(i * CD + su) * T + t]     = la0;
            o_lat[(size_t)b * (NCB * CD) * T + (size_t)(i * CD + su + 4) * T + t] = la1;
        }
        __syncthreads();

        // ---- build B fragments (en side) from es --------------------------
        bf16x8 bfrag[4][2];
        {
            const int dwo = (h & 1) * 2;
            const int tA  = h >> 1;
            const int tB  = 1 + (h >> 1);
#pragma unroll
            for (int pt = 0; pt < 4; ++pt) {
                const int col = pt * 16 + nl;
                uint2 lo0 = *reinterpret_cast<const uint2*>(&es[col * 12 + 0 * 4 + dwo]);
                uint2 hi0 = *reinterpret_cast<const uint2*>(&es[col * 12 + tA * 4 + dwo]);
                uint2 lh1 = *reinterpret_cast<const uint2*>(&es[col * 12 + tB * 4 + dwo]);
                uint4 t0v = make_uint4(lo0.x, lo0.y, hi0.x, hi0.y);
                uint4 t1v = make_uint4(lh1.x, lh1.y, lh1.x, lh1.y);
                bfrag[pt][0] = *reinterpret_cast<bf16x8*>(&t0v);
                bfrag[pt][1] = *reinterpret_cast<bf16x8*>(&t1v);
            }
        }

        // ---- MFMA search: wave su owns entries [su*256, su*256+256) -------
        // Dual accumulator chains (even/odd tiles) to break the loop-carried
        // select dependence; merged with explicit first-index tie-break.
        float best0[4] = {-3.0e38f, -3.0e38f, -3.0e38f, -3.0e38f};
        float best1[4] = {-3.0e38f, -3.0e38f, -3.0e38f, -3.0e38f};
        int   bidx0[4] = {0, 0, 0, 0};
        int   bidx1[4] = {0, 0, 0, 0};
        {
            const uint4* Ab = reinterpret_cast<const uint4*>(afr)
                              + ((size_t)(i * 64 + su * 16) * 2) * 64 + l;
            const f32x4* Hb = reinterpret_cast<const f32x4*>(h2c + (size_t)i * CB + su * 256);
            int eb = su * 256 + h * 4;
#pragma unroll 2
            for (int ep2 = 0; ep2 < 8; ++ep2) {
                uint4 uaa0 = Ab[0];     // tile 2*ep2   (chain 0)
                uint4 uaa1 = Ab[64];
                uint4 uba0 = Ab[128];   // tile 2*ep2+1 (chain 1)
                uint4 uba1 = Ab[192];
                f32x4 hva  = Hb[(2 * ep2) * 4 + h];
                f32x4 hvb  = Hb[(2 * ep2 + 1) * 4 + h];
                bf16x8 aa0 = *reinterpret_cast<bf16x8*>(&uaa0);
                bf16x8 aa1 = *reinterpret_cast<bf16x8*>(&uaa1);
                bf16x8 ba0 = *reinterpret_cast<bf16x8*>(&uba0);
                bf16x8 ba1 = *reinterpret_cast<bf16x8*>(&uba1);
#pragma unroll
                for (int pt = 0; pt < 4; ++pt) {
                    f32x4 accA = __builtin_amdgcn_mfma_f32_16x16x32_bf16(aa0, bfrag[pt][0], hva, 0, 0, 0);
                    accA = __builtin_amdgcn_mfma_f32_16x16x32_bf16(aa1, bfrag[pt][1], accA, 0, 0, 0);
                    f32x4 accB = __builtin_amdgcn_mfma_f32_16x16x32_bf16(ba0, bfrag[pt][0], hvb, 0, 0, 0);
                    accB = __builtin_amdgcn_mfma_f32_16x16x32_bf16(ba1, bfrag[pt][1], accB, 0, 0, 0);
#pragma unroll
                    for (int r = 0; r < 4; ++r) {
                        float scA = accA[r];
                        if (scA > best0[pt]) { best0[pt] = scA; bidx0[pt] = eb + r; }       // strict >: first idx
                        float scB = accB[r];
                        if (scB > best1[pt]) { best1[pt] = scB; bidx1[pt] = eb + 16 + r; }
                    }
                }
                Ab += 256; eb += 32;
            }
        }
        // merge even/odd chains (explicit tie-break, min index wins)
#pragma unroll
        for (int pt = 0; pt < 4; ++pt) {
            bool tk = (best1[pt] > best0[pt]) ||
                      (best1[pt] == best0[pt] && bidx1[pt] < bidx0[pt]);
            if (tk) { best0[pt] = best1[pt]; bidx0[pt] = bidx1[pt]; }
        }

        // wave-internal merge (explicit first-index tie-break)
#pragma unroll
        for (int off = 16; off <= 32; off <<= 1) {
#pragma unroll
            for (int pt = 0; pt < 4; ++pt) {
                float ob = __shfl_xor(best0[pt], off, 64);
                int   oi = __shfl_xor(bidx0[pt], off, 64);
                bool tk = (ob > best0[pt]) || (ob == best0[pt] && oi < bidx0[pt]);
                if (tk) { best0[pt] = ob; bidx0[pt] = oi; }
            }
        }
        if (l < 16) {
#pragma unroll
            for (int pt = 0; pt < 4; ++pt) {
                redS[su * 64 + pt * 16 + l] = best0[pt];
                redI[su * 64 + pt * 16 + l] = bidx0[pt];
            }
        }
        __syncthreads();

        // final reduce across 4 waves (ascending wave = ascending entry range)
        float bsc = redS[c];
        int   bi  = redI[c];
#pragma unroll
        for (int ww = 1; ww < 4; ++ww) {
            float v2 = redS[ww * TBLK + c];
            int   vi = redI[ww * TBLK + c];
            if (v2 > bsc) { bsc = v2; bi = vi; }
        }
        cidx[i * TBLK + c] = bi;   // benign multi-write of identical value
        if (s == 0) o_codes[(size_t)b * NCB * T + (size_t)i * T + t] = (float)bi;

        // gather raw codebook row; loss (once per column)
        float cv[CD];
        {
            const float4* cr4 = (const float4*)(codebook + ((size_t)i * CB + bi) * CD);
            float4 qa = cr4[0], qb = cr4[1];
            cv[0] = qa.x; cv[1] = qa.y; cv[2] = qa.z; cv[3] = qa.w;
            cv[4] = qb.x; cv[5] = qb.y; cv[6] = qb.z; cv[7] = qb.w;
            if (s == 0) {
#pragma unroll
                for (int j = 0; j < CD; ++j) {
                    float dd = cv[j] - Zl[(i * CD + j) * ZLS + c];
                    loss_local = fmaf(dd, dd, loss_local);
                }
            }
        }

        // ---- corrections: Z[row] -= CM[i][row] . cv, rows (i+1)*8 .. 71 ---
        {
            const int nf = 64 - 8 * i;
            for (int rr = su; rr < nf; rr += 4) {
                const int row = (i + 1) * 8 + rr;
                float zv = Zl[row * ZLS + c];
                const float* cm = CMt + ((size_t)i * 72 + row) * CD;
#pragma unroll
                for (int d2 = 0; d2 < CD; ++d2) zv = fmaf(-cm[d2], cv[d2], zv);
                Zl[row * ZLS + c] = zv;
            }
        }
    }
    __syncthreads();  // cidx complete

    // ================= final: z_q = obs + sum_i OP[i][code_i] ==============
    {
        f32x4 oa[8];
#pragma unroll
        for (int kb = 0; kb < 8; ++kb)
            oa[kb] = *reinterpret_cast<const f32x4*>(obs + su * 32 + kb * 4);
#pragma unroll
        for (int i2 = 0; i2 < NCB; ++i2) {
            int code = cidx[i2 * TBLK + c];
            const f32x4* op = reinterpret_cast<const f32x4*>(OPt + ((size_t)(i2 * CB + code)) * D + su * 32);
#pragma unroll
            for (int kb = 0; kb < 8; ++kb) oa[kb] += op[kb];
        }
        float* oq = o_zq + (size_t)b * D * T + (size_t)(su * 32) * T + t;
#pragma unroll
        for (int kb = 0; kb < 8; ++kb)
#pragma unroll
            for (int r = 0; r < 4; ++r)
                oq[(size_t)(kb * 4 + r) * T] = oa[kb][r];
    }

    // ================= scalar reductions ===================================
    float v = kl_local;
#pragma unroll
    for (int o = 32; o > 0; o >>= 1) v += __shfl_down(v, o, 64);
    float w2 = loss_local;
#pragma unroll
    for (int o = 32; o > 0; o >>= 1) w2 += __shfl_down(w2, o, 64);
    if ((tid & 63) == 0) { redw[s] = v; redw[4 + s] = w2; }
    __syncthreads();
    if (tid == 0) {
        float ks = redw[0] + redw[1] + redw[2] + redw[3];
        float ls = redw[4] + redw[5] + redw[6] + redw[7];
        atomicAdd(&o_scal[0], ks * (1.0f / 65536.0f));               // kl: /(B*T)
        float lsn = ls * (1.0f / (524288.0f * 9.0f));                // /(B*8*T)/NCB
        atomicAdd(&o_scal[1], lsn);                                  // commitment
        atomicAdd(&o_scal[2], lsn);                                  // codebook (identical in eval)
    }
}

extern "C" void kernel_launch(void* const* d_in, const int* in_sizes, int n_in,
                              void* d_out, int out_size, void* d_ws, size_t ws_size,
                              hipStream_t stream) {
    const float* x        = (const float*)d_in[0];
    const float* noise    = (const float*)d_in[1];
    const float* in_w     = (const float*)d_in[2];
    const float* in_b     = (const float*)d_in[3];
    const float* codebook = (const float*)d_in[4];
    const float* out_w    = (const float*)d_in[5];
    const float* out_b    = (const float*)d_in[6];

    float* out     = (float*)d_out;
    float* o_zq    = out + OFF_ZQ;
    float* o_scal  = out + OFF_SCAL;
    float* o_codes = out + OFF_CODES;
    float* o_lat   = out + OFF_LAT;

    unsigned* afr = (unsigned*)d_ws;
    float*    h2c = (float*)(afr + AFR_U32);
    unsigned* afw = (unsigned*)(h2c + H2C_F32);
    float*    CMt = (float*)(afw + AFW_U32);
    float*    obs = CMt + CM_F32;
    float*    bef = obs + OBS_F32;
    float*    OPt = bef + BEF_F32;

    const int prep_total = 2 * NCB * CB + NCB * 72 + 128 + 72 + 7680;  // 26960
    prep_kernel<<<(prep_total + 255) / 256, 256, 0, stream>>>(
        codebook, in_w, in_b, out_w, out_b, afr, h2c, afw, CMt, obs, bef, OPt, o_scal);

    dim3 grid(BB * (T / TBLK));  // 16 * 64 = 1024 blocks
    rvq_kernel<<<grid, NTHR, 0, stream>>>(x, noise, codebook,
                                          afr, h2c, afw, CMt, obs, bef, OPt,
                                          o_zq, o_scal, o_codes, o_lat);
}

// Round 7
// 385.891 us; speedup vs baseline: 2.0730x; 1.8329x over previous
//
#include <hip/hip_runtime.h>
#include <cstdint>
#include <cstddef>

// Problem constants (DAC RVQ VAE bottleneck)
constexpr int T   = 4096;
constexpr int BB  = 16;
constexpr int D   = 128;   // INPUT_DIM
constexpr int CB  = 1024;  // CODEBOOK_SIZE
constexpr int CD  = 8;     // CODEBOOK_DIM
constexpr int NCB = 9;     // N_CODEBOOKS

constexpr int TBLK = 64;   // columns (t positions) per block
constexpr int NTHR = 512;  // 8 waves
constexpr int NW   = 8;
constexpr int ZLS  = 66;   // Zl row stride (bank-conflict pad)

// Output layout (flat f32 concat, reference return order):
//   z_q [16*128*4096] | kl [1] | commit [1] | cbloss [1] | codes [16*9*4096] | latents [16*72*4096]
constexpr size_t OFF_ZQ    = 0;
constexpr size_t OFF_SCAL  = (size_t)BB * D * T;               // 8388608
constexpr size_t OFF_CODES = OFF_SCAL + 3;                     // 8388611
constexpr size_t OFF_LAT   = OFF_CODES + (size_t)BB * NCB * T; // 8978435

// Workspace layout (units: u32/f32), sequential:
//   afr [294912 u32] : search A-frags (codebook 3-term split)
//   h2c [9216 f32]   : -0.5*||cbn||^2 compact (per entry)
//   afw [30720 u32]  : Z-precompute A-frags (Wall 3-term split)
//   CMt [5184 f32]   : CM[j][72][8] = in_w_flat · out_w_j
//   obs [128 f32]    : sum_i out_b[i][.]
//   bef [72 f32]     : beff[row] = in_b[row] - sum_{j<i(row)} in_w[row]·out_b[j]
//   OPt [1179648 f32]: OP[i][e][128] = out_w_i · cb_i[e]
constexpr size_t AFR_U32 = (size_t)NCB * 64 * 2 * 64 * 4;  // 294912
constexpr size_t H2C_F32 = (size_t)NCB * CB;               // 9216
constexpr size_t AFW_U32 = (size_t)2 * 6 * 2 * 5 * 64 * 4; // 30720
constexpr size_t CM_F32  = (size_t)NCB * 72 * 8;           // 5184
constexpr size_t OBS_F32 = 128;
constexpr size_t BEF_F32 = 72;
constexpr size_t OP_F32  = (size_t)NCB * CB * D;           // 1179648

typedef short bf16x8 __attribute__((ext_vector_type(8)));
typedef float f32x4  __attribute__((ext_vector_type(4)));

__device__ __forceinline__ unsigned short f2bf(float f) {
    unsigned u = __float_as_uint(f);
    return (unsigned short)((u + (((u >> 16) & 1u) + 0x7FFFu)) >> 16);  // RNE
}
__device__ __forceinline__ float bf2f(unsigned short b) {
    return __uint_as_float((unsigned)b << 16);
}

// Z-precompute term pairs: (wA term, zB term). Dropped (1,2),(2,1),(2,2) ~2^-27/prod.
constexpr int PAIR_A[6] = {0, 0, 1, 1, 2, 0};
constexpr int PAIR_B[6] = {0, 1, 0, 1, 0, 2};

__device__ __forceinline__ unsigned short splitterm(float xv, int term) {
    unsigned short t0 = f2bf(xv); if (term == 0) return t0;
    float r1 = xv - bf2f(t0);
    unsigned short t1 = f2bf(r1); if (term == 1) return t1;
    float r2 = r1 - bf2f(t1);
    return f2bf(r2);
}

// ---------------------------------------------------------------------------
// Prep (single launch, role by flat id) — identical to round 3 (verified).
// ---------------------------------------------------------------------------
__global__ void prep_kernel(const float* __restrict__ codebook,
                            const float* __restrict__ in_w,
                            const float* __restrict__ in_b,
                            const float* __restrict__ out_w,
                            const float* __restrict__ out_b,
                            unsigned* __restrict__ afr,
                            float* __restrict__ h2c,
                            unsigned* __restrict__ afw,
                            float* __restrict__ CMt,
                            float* __restrict__ obs,
                            float* __restrict__ bef,
                            float* __restrict__ OPt,
                            float* __restrict__ scal) {
    const int gid = blockIdx.x * blockDim.x + threadIdx.x;
    if (gid == 0) { scal[0] = 0.f; scal[1] = 0.f; scal[2] = 0.f; }

    if (gid < NCB * CB) {
        const int e  = gid;
        const int i  = e >> 10;
        const int en = e & 1023;
        const int et = en >> 4;
        const int m  = en & 15;

        float v[CD]; float s2 = 0.f;
#pragma unroll
        for (int j = 0; j < CD; ++j) { v[j] = codebook[(size_t)e * CD + j]; s2 = fmaf(v[j], v[j], s2); }
        float inv = 1.0f / fmaxf(sqrtf(s2), 1e-12f);
        float cn[CD]; float c2 = 0.f;
#pragma unroll
        for (int j = 0; j < CD; ++j) { cn[j] = v[j] * inv; c2 = fmaf(cn[j], cn[j], c2); }
        h2c[e] = -0.5f * c2;  // exact fp32, negated (MFMA C-init)

        unsigned pk[3][4];
#pragma unroll
        for (int w = 0; w < 4; ++w) {
            float x0 = cn[2 * w], x1 = cn[2 * w + 1];
            unsigned short a0 = f2bf(x0); float r0 = x0 - bf2f(a0);
            unsigned short a1 = f2bf(r0); float q0 = r0 - bf2f(a1);
            unsigned short a2 = f2bf(q0);
            unsigned short b0 = f2bf(x1); float r1 = x1 - bf2f(b0);
            unsigned short b1 = f2bf(r1); float q1 = r1 - bf2f(b1);
            unsigned short b2 = f2bf(q1);
            pk[0][w] = (unsigned)a0 | ((unsigned)b0 << 16);
            pk[1][w] = (unsigned)a1 | ((unsigned)b1 << 16);
            pk[2][w] = (unsigned)a2 | ((unsigned)b2 << 16);
        }
        const int At[8] = {0, 1, 2, 0, 1, 0, 2, 1};
#pragma unroll
        for (int kh = 0; kh < 2; ++kh) {
#pragma unroll
            for (int h = 0; h < 4; ++h) {
                int A1 = At[kh * 4 + (h >> 1)];
                int A2 = At[kh * 4 + 2 + (h >> 1)];
                int dw = (h & 1) * 2;
                size_t off = ((((size_t)i * 64 + et) * 2 + kh) * 64 + (h * 16 + m)) * 4;
                afr[off + 0] = pk[A1][dw];
                afr[off + 1] = pk[A1][dw + 1];
                afr[off + 2] = pk[A2][dw];
                afr[off + 3] = pk[A2][dw + 1];
            }
        }
        return;
    }
    if (gid < 2 * NCB * CB) {
        const int e = gid - NCB * CB;
        const int i = e >> 10;
        float cv[CD];
#pragma unroll
        for (int d = 0; d < CD; ++d) cv[d] = codebook[(size_t)e * CD + d];
        const float* ow = out_w + (size_t)i * D * CD;
        float* dst = OPt + (size_t)e * D;
        for (int r = 0; r < D; ++r) {
            float a = 0.f;
#pragma unroll
            for (int d = 0; d < CD; ++d) a = fmaf(ow[r * CD + d], cv[d], a);
            dst[r] = a;
        }
        return;
    }
    if (gid < 2 * NCB * CB + NCB * 72) {
        const int idx = gid - 2 * NCB * CB;
        const int j = idx / 72, r = idx - j * 72;
        const float* wi = in_w + (size_t)r * D;
        const float* ow = out_w + (size_t)j * D * CD;
        float a[CD];
#pragma unroll
        for (int d = 0; d < CD; ++d) a[d] = 0.f;
        for (int k = 0; k < D; ++k) {
            float w = wi[k];
#pragma unroll
            for (int d = 0; d < CD; ++d) a[d] = fmaf(w, ow[k * CD + d], a[d]);
        }
#pragma unroll
        for (int d = 0; d < CD; ++d) CMt[((size_t)j * 72 + r) * CD + d] = a[d];
        return;
    }
    if (gid < 2 * NCB * CB + NCB * 72 + 128) {
        const int r = gid - (2 * NCB * CB + NCB * 72);
        float a = 0.f;
        for (int i = 0; i < NCB; ++i) a += out_b[(size_t)i * D + r];
        obs[r] = a;
        return;
    }
    if (gid < 2 * NCB * CB + NCB * 72 + 128 + 72) {
        const int row = gid - (2 * NCB * CB + NCB * 72 + 128);
        const int ic  = row >> 3;
        const float* wi = in_w + (size_t)row * D;
        float a = in_b[row];
        for (int j = 0; j < ic; ++j) {
            const float* ob = out_b + (size_t)j * D;
            float s = 0.f;
            for (int k = 0; k < D; ++k) s = fmaf(wi[k], ob[k], s);
            a -= s;
        }
        bef[row] = a;
        return;
    }
    if (gid < 2 * NCB * CB + NCB * 72 + 128 + 72 + 7680) {
        int idx = gid - (2 * NCB * CB + NCB * 72 + 128 + 72);
        const int lane = idx & 63; idx >>= 6;
        const int mt = idx % 5; idx /= 5;
        const int kq = idx & 1; idx >>= 1;
        const int p  = idx % 6;
        const int P  = idx / 6;
        const int h  = lane >> 4, m = lane & 15;
        const int row = mt * 16 + m;
        const int term = PAIR_A[p];
        const int D0 = P * 64 + kq * 32 + h * 4;
        const int doff[4][2] = {{0, 1}, {2, 3}, {16, 17}, {18, 19}};
        unsigned wv[4];
#pragma unroll
        for (int w = 0; w < 4; ++w) {
            unsigned short lo = 0, hi = 0;
            if (row < 72) {
                lo = splitterm(in_w[(size_t)row * D + D0 + doff[w][0]], term);
                hi = splitterm(in_w[(size_t)row * D + D0 + doff[w][1]], term);
            }
            wv[w] = (unsigned)lo | ((unsigned)hi << 16);
        }
        *reinterpret_cast<uint4*>(afw + ((size_t)(((P * 6 + p) * 2 + kq) * 5 + mt) * 64 + lane) * 4)
            = make_uint4(wv[0], wv[1], wv[2], wv[3]);
        return;
    }
}

// ---------------------------------------------------------------------------
// Main fused kernel — 8 waves per block; occupancy from block shape
// (4 blk/CU x 8 waves = 32 waves/CU by wave-slot limit), NOT from the
// min-waves launch-bounds hint (which over-constrains the allocator:
// (512,8) -> 32 VGPR + spills in round 4; (256,6) -> 40 VGPR + spills in
// round 6). Cap here is permissive: (512,4) -> 128 VGPR.
// ---------------------------------------------------------------------------
__global__ __launch_bounds__(NTHR, 4)
void rvq_kernel(const float* __restrict__ x,
                const float* __restrict__ noise,
                const float* __restrict__ codebook,
                const unsigned* __restrict__ afr,
                const float* __restrict__ h2c,
                const unsigned* __restrict__ afw,
                const float* __restrict__ CMt,
                const float* __restrict__ obs,
                const float* __restrict__ bef,
                const float* __restrict__ OPt,
                float* __restrict__ o_zq,
                float* __restrict__ o_scal,
                float* __restrict__ o_codes,
                float* __restrict__ o_lat) {
    __shared__ char     zbuf[24576];        // union: zs (24KB) then Zl (80x66 f32, 21.1KB)
    __shared__ unsigned es[TBLK * 12];      // split en: [col][3 terms][4xu32] (3 KB)
    __shared__ float    redS[NW * TBLK];    // per-wave best score (2 KB)
    __shared__ int      redI[NW * TBLK];    // per-wave best index (2 KB)
    __shared__ int      cidx[NCB * TBLK];   // selected codes (2.25 KB)
    __shared__ float    redw[2 * NW];

    uint2* zs = reinterpret_cast<uint2*>(zbuf);   // [(term*16+slot)*64 + col]
    float* Zl = reinterpret_cast<float*>(zbuf);   // [row*ZLS + col]

    const int tid = threadIdx.x;
    const int c   = tid & 63;            // column for col-parallel phases
    const int s   = tid >> 6;            // wave id (0..7)
    const int su  = __builtin_amdgcn_readfirstlane(s);
    const int b   = blockIdx.x >> 6;
    const int t0  = (blockIdx.x & 63) << 6;
    const int t   = t0 + c;

    const int l  = tid & 63;             // lane
    const int h  = l >> 4;               // 16-lane group
    const int nl = l & 15;               // position-within-tile

    // ================= Phase Z: Z = Wall * z + beff (MFMA) =================
    // Consume mapping: waves 0-3 -> N-tile su, mt 0..2; waves 4-7 -> N-tile su-4, mt 3..4.
    const int mtbase = (su < 4) ? 0 : 3;
    const int nmt    = (su < 4) ? 3 : 2;
    float kl_local = 0.f;
    f32x4 acc[3];
#pragma unroll
    for (int q = 0; q < 3; ++q) {
        int row0 = (mtbase + q) * 16 + h * 4;
        if (q < nmt && row0 < 72) acc[q] = *reinterpret_cast<const f32x4*>(bef + row0);
        else                      acc[q] = f32x4{0.f, 0.f, 0.f, 0.f};
    }

#pragma unroll 1
    for (int P = 0; P < 2; ++P) {
        // ---- produce: rows P*64 + su*8 .. +7, col c ----
        {
            const int r0 = P * 64 + su * 8;
            const float* xm = x     + (size_t)b * 2 * D * T + (size_t)r0 * T + t;
            const float* xs = xm    + (size_t)D * T;
            const float* nz = noise + (size_t)b * D * T     + (size_t)r0 * T + t;
            float zrow[8];
#pragma unroll
            for (int k = 0; k < 8; ++k) {
                float m  = xm[(size_t)k * T];
                float sc = xs[(size_t)k * T];
                float nv = nz[(size_t)k * T];
                float sp  = fmaxf(sc, 0.f) + log1pf(expf(-fabsf(sc)));  // softplus
                float sd  = sp + 1e-4f;
                float var = sd * sd;
                zrow[k]   = fmaf(nv, sd, m);
                kl_local += m * m + var - logf(var) - 1.0f;
            }
#pragma unroll
            for (int db = 0; db < 2; ++db) {
                unsigned w[3][2];
#pragma unroll
                for (int half = 0; half < 2; ++half) {
                    float x0 = zrow[db * 4 + half * 2], x1 = zrow[db * 4 + half * 2 + 1];
                    unsigned short a0 = f2bf(x0); float r1 = x0 - bf2f(a0);
                    unsigned short a1 = f2bf(r1); float r2 = r1 - bf2f(a1);
                    unsigned short a2 = f2bf(r2);
                    unsigned short b0 = f2bf(x1); float s1v = x1 - bf2f(b0);
                    unsigned short b1 = f2bf(s1v); float s2v = s1v - bf2f(b1);
                    unsigned short b2 = f2bf(s2v);
                    w[0][half] = (unsigned)a0 | ((unsigned)b0 << 16);
                    w[1][half] = (unsigned)a1 | ((unsigned)b1 << 16);
                    w[2][half] = (unsigned)a2 | ((unsigned)b2 << 16);
                }
#pragma unroll
                for (int tt = 0; tt < 3; ++tt)
                    zs[(tt * 16 + su * 2 + db) * 64 + c] = make_uint2(w[tt][0], w[tt][1]);
            }
        }
        __syncthreads();
        // ---- consume: wave su -> N-tile (su&3), mt range [mtbase, mtbase+nmt) ----
        {
            const int colB = (su & 3) * 16 + nl;
#pragma unroll
            for (int p = 0; p < 6; ++p) {
#pragma unroll
                for (int kq = 0; kq < 2; ++kq) {
                    uint2 blo = zs[(PAIR_B[p] * 16 + kq * 8 + h) * 64 + colB];
                    uint2 bhi = zs[(PAIR_B[p] * 16 + kq * 8 + 4 + h) * 64 + colB];
                    uint4 bu = make_uint4(blo.x, blo.y, bhi.x, bhi.y);
                    bf16x8 bfr = *reinterpret_cast<bf16x8*>(&bu);
                    const uint4* Aw = reinterpret_cast<const uint4*>(afw)
                                      + (size_t)(((P * 6 + p) * 2 + kq) * 5) * 64 + l;
#pragma unroll
                    for (int q = 0; q < 3; ++q) {
                        if (q < nmt) {
                            uint4 au = Aw[(size_t)(mtbase + q) * 64];
                            bf16x8 af = *reinterpret_cast<bf16x8*>(&au);
                            acc[q] = __builtin_amdgcn_mfma_f32_16x16x32_bf16(af, bfr, acc[q], 0, 0, 0);
                        }
                    }
                }
            }
        }
        __syncthreads();   // zs consumed (pass-1 rewrites / Zl overlays)
    }
    // ---- Zl store (overlays zs; all reads done) ----
#pragma unroll
    for (int q = 0; q < 3; ++q) {
        if (q < nmt) {
#pragma unroll
            for (int r = 0; r < 4; ++r)
                Zl[((mtbase + q) * 16 + h * 4 + r) * ZLS + (su & 3) * 16 + nl] = acc[q][r];
        }
    }

    float loss_local = 0.f;

    // ================= RVQ loop over 9 codebooks ===========================
    for (int i = 0; i < NCB; ++i) {
        __syncthreads();  // Zl rows current (corrections of i-1 done)

        // ---- split phase: normalize z_e, 3-term bf16 split into es --------
        if (tid < 64) {
            float v[CD]; float n2 = 0.f;
#pragma unroll
            for (int j = 0; j < CD; ++j) { v[j] = Zl[(i * CD + j) * ZLS + tid]; n2 = fmaf(v[j], v[j], n2); }
            float inv = 1.0f / fmaxf(sqrtf(n2), 1e-12f);
            unsigned pk[3][4];
#pragma unroll
            for (int w = 0; w < 4; ++w) {
                float x0 = v[2 * w] * inv, x1 = v[2 * w + 1] * inv;
                unsigned short a0 = f2bf(x0); float r0 = x0 - bf2f(a0);
                unsigned short a1 = f2bf(r0); float q0 = r0 - bf2f(a1);
                unsigned short a2 = f2bf(q0);
                unsigned short b0 = f2bf(x1); float r1 = x1 - bf2f(b0);
                unsigned short b1 = f2bf(r1); float q1 = r1 - bf2f(b1);
                unsigned short b2 = f2bf(q1);
                pk[0][w] = (unsigned)a0 | ((unsigned)b0 << 16);
                pk[1][w] = (unsigned)a1 | ((unsigned)b1 << 16);
                pk[2][w] = (unsigned)a2 | ((unsigned)b2 << 16);
            }
            uint4* ep = reinterpret_cast<uint4*>(&es[(size_t)tid * 12]);
            ep[0] = make_uint4(pk[0][0], pk[0][1], pk[0][2], pk[0][3]);
            ep[1] = make_uint4(pk[1][0], pk[1][1], pk[1][2], pk[1][3]);
            ep[2] = make_uint4(pk[2][0], pk[2][1], pk[2][2], pk[2][3]);
        }
        // ---- latents output: wave su writes z_e row su for all 64 cols ----
        {
            float la = Zl[(i * CD + su) * ZLS + c];
            o_lat[(size_t)b * (NCB * CD) * T + (size_t)(i * CD + su) * T + t] = la;
        }
        __syncthreads();

        // ---- build B fragments (en side) from es --------------------------
        bf16x8 bfrag[4][2];
        {
            const int dwo = (h & 1) * 2;
            const int tA  = h >> 1;
            const int tB  = 1 + (h >> 1);
#pragma unroll
            for (int pt = 0; pt < 4; ++pt) {
                const int col = pt * 16 + nl;
                uint2 lo0 = *reinterpret_cast<const uint2*>(&es[col * 12 + 0 * 4 + dwo]);
                uint2 hi0 = *reinterpret_cast<const uint2*>(&es[col * 12 + tA * 4 + dwo]);
                uint2 lh1 = *reinterpret_cast<const uint2*>(&es[col * 12 + tB * 4 + dwo]);
                uint4 t0v = make_uint4(lo0.x, lo0.y, hi0.x, hi0.y);
                uint4 t1v = make_uint4(lh1.x, lh1.y, lh1.x, lh1.y);
                bfrag[pt][0] = *reinterpret_cast<bf16x8*>(&t0v);
                bfrag[pt][1] = *reinterpret_cast<bf16x8*>(&t1v);
            }
        }

        // ---- MFMA search: wave su owns entries [su*128, su*128+128) -------
        float best[4] = {-3.0e38f, -3.0e38f, -3.0e38f, -3.0e38f};
        int   bidx[4] = {0, 0, 0, 0};
        {
            const uint4* Ab = reinterpret_cast<const uint4*>(afr)
                              + ((size_t)(i * 64 + su * 8) * 2) * 64 + l;
            const f32x4* Hb = reinterpret_cast<const f32x4*>(h2c)
                              + (size_t)i * 256 + su * 32;
            int eb = su * 128 + h * 4;   // entry index base for reg 0
#pragma unroll 2
            for (int e8 = 0; e8 < 8; ++e8) {
                uint4 ua0 = Ab[0];     // kh0 A-fragment (16B/lane, coalesced)
                uint4 ua1 = Ab[64];    // kh1 A-fragment
                f32x4 hv  = Hb[e8 * 4 + h];   // exact -h2 as C-init
                bf16x8 a0 = *reinterpret_cast<bf16x8*>(&ua0);
                bf16x8 a1 = *reinterpret_cast<bf16x8*>(&ua1);
#pragma unroll
                for (int pt = 0; pt < 4; ++pt) {
                    f32x4 accd = __builtin_amdgcn_mfma_f32_16x16x32_bf16(a0, bfrag[pt][0], hv, 0, 0, 0);
                    accd = __builtin_amdgcn_mfma_f32_16x16x32_bf16(a1, bfrag[pt][1], accd, 0, 0, 0);
#pragma unroll
                    for (int r = 0; r < 4; ++r) {
                        float sc = accd[r];
                        if (sc > best[pt]) { best[pt] = sc; bidx[pt] = eb + r; }  // strict >: first idx
                    }
                }
                Ab += 128; eb += 16;
            }
        }

        // wave-internal merge (explicit first-index tie-break)
#pragma unroll
        for (int off = 16; off <= 32; off <<= 1) {
#pragma unroll
            for (int pt = 0; pt < 4; ++pt) {
                float ob = __shfl_xor(best[pt], off, 64);
                int   oi = __shfl_xor(bidx[pt], off, 64);
                bool tk = (ob > best[pt]) || (ob == best[pt] && oi < bidx[pt]);
                if (tk) { best[pt] = ob; bidx[pt] = oi; }
            }
        }
        if (l < 16) {
#pragma unroll
            for (int pt = 0; pt < 4; ++pt) {
                redS[su * 64 + pt * 16 + l] = best[pt];
                redI[su * 64 + pt * 16 + l] = bidx[pt];
            }
        }
        __syncthreads();

        // final reduce across 8 waves (ascending wave = ascending entry range)
        float bsc = redS[c];
        int   bi  = redI[c];
#pragma unroll
        for (int ww = 1; ww < NW; ++ww) {
            float v2 = redS[ww * TBLK + c];
            int   vi = redI[ww * TBLK + c];
            if (v2 > bsc) { bsc = v2; bi = vi; }
        }
        cidx[i * TBLK + c] = bi;   // benign multi-write of identical value
        if (s == 0) o_codes[(size_t)b * NCB * T + (size_t)i * T + t] = (float)bi;

        // gather raw codebook row; loss (once per column)
        float cv[CD];
        {
            const float4* cr4 = (const float4*)(codebook + ((size_t)i * CB + bi) * CD);
            float4 qa = cr4[0], qb = cr4[1];
            cv[0] = qa.x; cv[1] = qa.y; cv[2] = qa.z; cv[3] = qa.w;
            cv[4] = qb.x; cv[5] = qb.y; cv[6] = qb.z; cv[7] = qb.w;
            if (s == 0) {
#pragma unroll
                for (int j = 0; j < CD; ++j) {
                    float dd = cv[j] - Zl[(i * CD + j) * ZLS + c];
                    loss_local = fmaf(dd, dd, loss_local);
                }
            }
        }

        // ---- corrections: Z[row] -= CM[i][row] . cv, rows (i+1)*8 .. 71 ---
        {
            const int nf = 64 - 8 * i;
            for (int rr = su; rr < nf; rr += NW) {
                const int row = (i + 1) * 8 + rr;
                float zv = Zl[row * ZLS + c];
                const float* cm = CMt + ((size_t)i * 72 + row) * CD;
#pragma unroll
                for (int d2 = 0; d2 < CD; ++d2) zv = fmaf(-cm[d2], cv[d2], zv);
                Zl[row * ZLS + c] = zv;
            }
        }
    }
    __syncthreads();  // cidx complete

    // ================= final: z_q = obs + sum_i OP[i][code_i] ==============
    {
        f32x4 oa[4];
#pragma unroll
        for (int kb = 0; kb < 4; ++kb)
            oa[kb] = *reinterpret_cast<const f32x4*>(obs + su * 16 + kb * 4);
#pragma unroll
        for (int i2 = 0; i2 < NCB; ++i2) {
            int code = cidx[i2 * TBLK + c];
            const f32x4* op = reinterpret_cast<const f32x4*>(OPt + ((size_t)(i2 * CB + code)) * D + su * 16);
#pragma unroll
            for (int kb = 0; kb < 4; ++kb) oa[kb] += op[kb];
        }
        float* oq = o_zq + (size_t)b * D * T + (size_t)(su * 16) * T + t;
#pragma unroll
        for (int kb = 0; kb < 4; ++kb)
#pragma unroll
            for (int r = 0; r < 4; ++r)
                oq[(size_t)(kb * 4 + r) * T] = oa[kb][r];
    }

    // ================= scalar reductions ===================================
    float v = kl_local;
#pragma unroll
    for (int o = 32; o > 0; o >>= 1) v += __shfl_down(v, o, 64);
    float w2 = loss_local;
#pragma unroll
    for (int o = 32; o > 0; o >>= 1) w2 += __shfl_down(w2, o, 64);
    if ((tid & 63) == 0) { redw[s] = v; redw[NW + s] = w2; }
    __syncthreads();
    if (tid == 0) {
        float ks = 0.f, ls = 0.f;
#pragma unroll
        for (int q = 0; q < NW; ++q) { ks += redw[q]; ls += redw[NW + q]; }
        atomicAdd(&o_scal[0], ks * (1.0f / 65536.0f));               // kl: /(B*T)
        float lsn = ls * (1.0f / (524288.0f * 9.0f));                // /(B*8*T)/NCB
        atomicAdd(&o_scal[1], lsn);                                  // commitment
        atomicAdd(&o_scal[2], lsn);                                  // codebook (identical in eval)
    }
}

extern "C" void kernel_launch(void* const* d_in, const int* in_sizes, int n_in,
                              void* d_out, int out_size, void* d_ws, size_t ws_size,
                              hipStream_t stream) {
    const float* x        = (const float*)d_in[0];
    const float* noise    = (const float*)d_in[1];
    const float* in_w     = (const float*)d_in[2];
    const float* in_b     = (const float*)d_in[3];
    const float* codebook = (const float*)d_in[4];
    const float* out_w    = (const float*)d_in[5];
    const float* out_b    = (const float*)d_in[6];

    float* out     = (float*)d_out;
    float* o_zq    = out + OFF_ZQ;
    float* o_scal  = out + OFF_SCAL;
    float* o_codes = out + OFF_CODES;
    float* o_lat   = out + OFF_LAT;

    unsigned* afr = (unsigned*)d_ws;
    float*    h2c = (float*)(afr + AFR_U32);
    unsigned* afw = (unsigned*)(h2c + H2C_F32);
    float*    CMt = (float*)(afw + AFW_U32);
    float*    obs = CMt + CM_F32;
    float*    bef = obs + OBS_F32;
    float*    OPt = bef + BEF_F32;

    const int prep_total = 2 * NCB * CB + NCB * 72 + 128 + 72 + 7680;  // 26960
    prep_kernel<<<(prep_total + 255) / 256, 256, 0, stream>>>(
        codebook, in_w, in_b, out_w, out_b, afr, h2c, afw, CMt, obs, bef, OPt, o_scal);

    dim3 grid(BB * (T / TBLK));  // 16 * 64 = 1024 blocks
    rvq_kernel<<<grid, NTHR, 0, stream>>>(x, noise, codebook,
                                          afr, h2c, afw, CMt, obs, bef, OPt,
                                          o_zq, o_scal, o_codes, o_lat);
}

// Round 9
// 363.316 us; speedup vs baseline: 2.2018x; 1.0621x over previous
//
#include <hip/hip_runtime.h>
#include <cstdint>
#include <cstddef>

// Problem constants (DAC RVQ VAE bottleneck)
constexpr int T   = 4096;
constexpr int BB  = 16;
constexpr int D   = 128;   // INPUT_DIM
constexpr int CB  = 1024;  // CODEBOOK_SIZE
constexpr int CD  = 8;     // CODEBOOK_DIM
constexpr int NCB = 9;     // N_CODEBOOKS

constexpr int TBLK = 64;   // columns (t positions) per tile
constexpr int NTHR = 512;  // 8 waves
constexpr int NW   = 8;
constexpr int ZLS  = 66;   // Zl row stride (bank-conflict pad)

// Output layout (flat f32 concat, reference return order):
//   z_q [16*128*4096] | kl [1] | commit [1] | cbloss [1] | codes [16*9*4096] | latents [16*72*4096]
constexpr size_t OFF_ZQ    = 0;
constexpr size_t OFF_SCAL  = (size_t)BB * D * T;               // 8388608
constexpr size_t OFF_CODES = OFF_SCAL + 3;                     // 8388611
constexpr size_t OFF_LAT   = OFF_CODES + (size_t)BB * NCB * T; // 8978435

// Workspace layout (units: u32/f32), sequential:
//   afr [294912 u32] : search A-frags (codebook 3-term split)
//   h2c [9216 f32]   : -0.5*||cbn||^2 compact (per entry)
//   afw [30720 u32]  : Z-precompute A-frags (Wall 3-term split)
//   CMt [5184 f32]   : CM[j][72][8] = in_w_flat · out_w_j
//   obs [128 f32]    : sum_i out_b[i][.]
//   bef [72 f32]     : beff[row] = in_b[row] - sum_{j<i(row)} in_w[row]·out_b[j]
//   OPt [1179648 f32]: OP[i][e][128] = out_w_i · cb_i[e]
constexpr size_t AFR_U32 = (size_t)NCB * 64 * 2 * 64 * 4;  // 294912
constexpr size_t H2C_F32 = (size_t)NCB * CB;               // 9216
constexpr size_t AFW_U32 = (size_t)2 * 6 * 2 * 5 * 64 * 4; // 30720
constexpr size_t CM_F32  = (size_t)NCB * 72 * 8;           // 5184
constexpr size_t OBS_F32 = 128;
constexpr size_t BEF_F32 = 72;
constexpr size_t OP_F32  = (size_t)NCB * CB * D;           // 1179648

typedef short bf16x8 __attribute__((ext_vector_type(8)));
typedef float f32x4  __attribute__((ext_vector_type(4)));

__device__ __forceinline__ unsigned short f2bf(float f) {
    unsigned u = __float_as_uint(f);
    return (unsigned short)((u + (((u >> 16) & 1u) + 0x7FFFu)) >> 16);  // RNE
}
__device__ __forceinline__ float bf2f(unsigned short b) {
    return __uint_as_float((unsigned)b << 16);
}

// Z-precompute term pairs: (wA term, zB term). Dropped (1,2),(2,1),(2,2) ~2^-27/prod.
constexpr int PAIR_A[6] = {0, 0, 1, 1, 2, 0};
constexpr int PAIR_B[6] = {0, 1, 0, 1, 0, 2};

__device__ __forceinline__ unsigned short splitterm(float xv, int term) {
    unsigned short t0 = f2bf(xv); if (term == 0) return t0;
    float r1 = xv - bf2f(t0);
    unsigned short t1 = f2bf(r1); if (term == 1) return t1;
    float r2 = r1 - bf2f(t1);
    return f2bf(r2);
}

// ---------------------------------------------------------------------------
// Prep (single launch, role by flat id) — identical to round 3 (verified).
// ---------------------------------------------------------------------------
__global__ void prep_kernel(const float* __restrict__ codebook,
                            const float* __restrict__ in_w,
                            const float* __restrict__ in_b,
                            const float* __restrict__ out_w,
                            const float* __restrict__ out_b,
                            unsigned* __restrict__ afr,
                            float* __restrict__ h2c,
                            unsigned* __restrict__ afw,
                            float* __restrict__ CMt,
                            float* __restrict__ obs,
                            float* __restrict__ bef,
                            float* __restrict__ OPt,
                            float* __restrict__ scal) {
    const int gid = blockIdx.x * blockDim.x + threadIdx.x;
    if (gid == 0) { scal[0] = 0.f; scal[1] = 0.f; scal[2] = 0.f; }

    if (gid < NCB * CB) {
        const int e  = gid;
        const int i  = e >> 10;
        const int en = e & 1023;
        const int et = en >> 4;
        const int m  = en & 15;

        float v[CD]; float s2 = 0.f;
#pragma unroll
        for (int j = 0; j < CD; ++j) { v[j] = codebook[(size_t)e * CD + j]; s2 = fmaf(v[j], v[j], s2); }
        float inv = 1.0f / fmaxf(sqrtf(s2), 1e-12f);
        float cn[CD]; float c2 = 0.f;
#pragma unroll
        for (int j = 0; j < CD; ++j) { cn[j] = v[j] * inv; c2 = fmaf(cn[j], cn[j], c2); }
        h2c[e] = -0.5f * c2;  // exact fp32, negated (MFMA C-init)

        unsigned pk[3][4];
#pragma unroll
        for (int w = 0; w < 4; ++w) {
            float x0 = cn[2 * w], x1 = cn[2 * w + 1];
            unsigned short a0 = f2bf(x0); float r0 = x0 - bf2f(a0);
            unsigned short a1 = f2bf(r0); float q0 = r0 - bf2f(a1);
            unsigned short a2 = f2bf(q0);
            unsigned short b0 = f2bf(x1); float r1 = x1 - bf2f(b0);
            unsigned short b1 = f2bf(r1); float q1 = r1 - bf2f(b1);
            unsigned short b2 = f2bf(q1);
            pk[0][w] = (unsigned)a0 | ((unsigned)b0 << 16);
            pk[1][w] = (unsigned)a1 | ((unsigned)b1 << 16);
            pk[2][w] = (unsigned)a2 | ((unsigned)b2 << 16);
        }
        const int At[8] = {0, 1, 2, 0, 1, 0, 2, 1};
#pragma unroll
        for (int kh = 0; kh < 2; ++kh) {
#pragma unroll
            for (int h = 0; h < 4; ++h) {
                int A1 = At[kh * 4 + (h >> 1)];
                int A2 = At[kh * 4 + 2 + (h >> 1)];
                int dw = (h & 1) * 2;
                size_t off = ((((size_t)i * 64 + et) * 2 + kh) * 64 + (h * 16 + m)) * 4;
                afr[off + 0] = pk[A1][dw];
                afr[off + 1] = pk[A1][dw + 1];
                afr[off + 2] = pk[A2][dw];
                afr[off + 3] = pk[A2][dw + 1];
            }
        }
        return;
    }
    if (gid < 2 * NCB * CB) {
        const int e = gid - NCB * CB;
        const int i = e >> 10;
        float cv[CD];
#pragma unroll
        for (int d = 0; d < CD; ++d) cv[d] = codebook[(size_t)e * CD + d];
        const float* ow = out_w + (size_t)i * D * CD;
        float* dst = OPt + (size_t)e * D;
        for (int r = 0; r < D; ++r) {
            float a = 0.f;
#pragma unroll
            for (int d = 0; d < CD; ++d) a = fmaf(ow[r * CD + d], cv[d], a);
            dst[r] = a;
        }
        return;
    }
    if (gid < 2 * NCB * CB + NCB * 72) {
        const int idx = gid - 2 * NCB * CB;
        const int j = idx / 72, r = idx - j * 72;
        const float* wi = in_w + (size_t)r * D;
        const float* ow = out_w + (size_t)j * D * CD;
        float a[CD];
#pragma unroll
        for (int d = 0; d < CD; ++d) a[d] = 0.f;
        for (int k = 0; k < D; ++k) {
            float w = wi[k];
#pragma unroll
            for (int d = 0; d < CD; ++d) a[d] = fmaf(w, ow[k * CD + d], a[d]);
        }
#pragma unroll
        for (int d = 0; d < CD; ++d) CMt[((size_t)j * 72 + r) * CD + d] = a[d];
        return;
    }
    if (gid < 2 * NCB * CB + NCB * 72 + 128) {
        const int r = gid - (2 * NCB * CB + NCB * 72);
        float a = 0.f;
        for (int i = 0; i < NCB; ++i) a += out_b[(size_t)i * D + r];
        obs[r] = a;
        return;
    }
    if (gid < 2 * NCB * CB + NCB * 72 + 128 + 72) {
        const int row = gid - (2 * NCB * CB + NCB * 72 + 128);
        const int ic  = row >> 3;
        const float* wi = in_w + (size_t)row * D;
        float a = in_b[row];
        for (int j = 0; j < ic; ++j) {
            const float* ob = out_b + (size_t)j * D;
            float s = 0.f;
            for (int k = 0; k < D; ++k) s = fmaf(wi[k], ob[k], s);
            a -= s;
        }
        bef[row] = a;
        return;
    }
    if (gid < 2 * NCB * CB + NCB * 72 + 128 + 72 + 7680) {
        int idx = gid - (2 * NCB * CB + NCB * 72 + 128 + 72);
        const int lane = idx & 63; idx >>= 6;
        const int mt = idx % 5; idx /= 5;
        const int kq = idx & 1; idx >>= 1;
        const int p  = idx % 6;
        const int P  = idx / 6;
        const int h  = lane >> 4, m = lane & 15;
        const int row = mt * 16 + m;
        const int term = PAIR_A[p];
        const int D0 = P * 64 + kq * 32 + h * 4;
        const int doff[4][2] = {{0, 1}, {2, 3}, {16, 17}, {18, 19}};
        unsigned wv[4];
#pragma unroll
        for (int w = 0; w < 4; ++w) {
            unsigned short lo = 0, hi = 0;
            if (row < 72) {
                lo = splitterm(in_w[(size_t)row * D + D0 + doff[w][0]], term);
                hi = splitterm(in_w[(size_t)row * D + D0 + doff[w][1]], term);
            }
            wv[w] = (unsigned)lo | ((unsigned)hi << 16);
        }
        *reinterpret_cast<uint4*>(afw + ((size_t)(((P * 6 + p) * 2 + kq) * 5 + mt) * 64 + lane) * 4)
            = make_uint4(wv[0], wv[1], wv[2], wv[3]);
        return;
    }
}

// ---------------------------------------------------------------------------
// Main fused kernel — 8 waves per block, TWO t-tiles per block (ILP between
// barriers; residency is VGPR+AGPR-capped at ~16 waves/CU so we add work per
// wave, not waves). Waves 0-3 own tile A's reduce/gather/corrections/z_q;
// waves 4-7 own tile B's. Search processes both tiles per codebook-fragment
// load (2x amortization of ua0/ua1/hv).
// LDS map in sbuf[62592]:
//   phase Z : zs [48][64] uint2 @ 0        (24576 B, scratch per tile)
//   RVQ loop: esA @ 0 (3072) | esB @ 3072 | redS @ 6144 (4096: [2][8][64])
//             redI @ 10240 (4096) | cidx @ 14336 ([2][9][64] = 4608)
//             redw @ 18944 (64)
//   ZlA [72][66] f32 @ 24576 (19008) | ZlB @ 43584 (19008)
// ---------------------------------------------------------------------------
__global__ __launch_bounds__(NTHR, 4)
void rvq_kernel(const float* __restrict__ x,
                const float* __restrict__ noise,
                const float* __restrict__ codebook,
                const unsigned* __restrict__ afr,
                const float* __restrict__ h2c,
                const unsigned* __restrict__ afw,
                const float* __restrict__ CMt,
                const float* __restrict__ obs,
                const float* __restrict__ bef,
                const float* __restrict__ OPt,
                float* __restrict__ o_zq,
                float* __restrict__ o_scal,
                float* __restrict__ o_codes,
                float* __restrict__ o_lat) {
    __shared__ char sbuf[24576 + 2 * 19008];

    uint2*    zs   = reinterpret_cast<uint2*>(sbuf);
    unsigned* esA  = reinterpret_cast<unsigned*>(sbuf);
    unsigned* esB  = reinterpret_cast<unsigned*>(sbuf + 3072);
    float*    redS = reinterpret_cast<float*>(sbuf + 6144);   // [(tile*8+wave)*64 + idx]
    int*      redI = reinterpret_cast<int*>(sbuf + 10240);
    int*      cidx = reinterpret_cast<int*>(sbuf + 14336);    // [(tile*9+i)*64 + c]
    float*    redw = reinterpret_cast<float*>(sbuf + 18944);
    float*    ZlA  = reinterpret_cast<float*>(sbuf + 24576);
    float*    ZlB  = reinterpret_cast<float*>(sbuf + 24576 + 19008);

    const int tid = threadIdx.x;
    const int c   = tid & 63;            // column for col-parallel phases
    const int s   = tid >> 6;            // wave id (0..7)
    const int su  = __builtin_amdgcn_readfirstlane(s);
    const int b   = blockIdx.x >> 5;
    const int t0  = (blockIdx.x & 31) << 7;   // 128 t-positions per block

    const int l  = tid & 63;             // lane
    const int h  = l >> 4;               // 16-lane group
    const int nl = l & 15;               // position-within-tile

    // ================= Phase Z per tile: Z = Wall * z + beff (MFMA) ========
    const int mtbase = (su < 4) ? 0 : 3;
    const int nmt    = (su < 4) ? 3 : 2;
    float kl_local = 0.f;

#pragma unroll 1
    for (int tl = 0; tl < 2; ++tl) {
        float* Zl = tl ? ZlB : ZlA;
        const int t = t0 + tl * 64 + c;
        f32x4 acc[3];
#pragma unroll
        for (int q = 0; q < 3; ++q) {
            int row0 = (mtbase + q) * 16 + h * 4;
            if (q < nmt && row0 < 72) acc[q] = *reinterpret_cast<const f32x4*>(bef + row0);
            else                      acc[q] = f32x4{0.f, 0.f, 0.f, 0.f};
        }

#pragma unroll 1
        for (int P = 0; P < 2; ++P) {
            // ---- produce: rows P*64 + su*8 .. +7, col c ----
            {
                const int r0 = P * 64 + su * 8;
                const float* xm = x     + (size_t)b * 2 * D * T + (size_t)r0 * T + t;
                const float* xs = xm    + (size_t)D * T;
                const float* nz = noise + (size_t)b * D * T     + (size_t)r0 * T + t;
                float zrow[8];
#pragma unroll
                for (int k = 0; k < 8; ++k) {
                    float m  = xm[(size_t)k * T];
                    float sc = xs[(size_t)k * T];
                    float nv = nz[(size_t)k * T];
                    float sp  = fmaxf(sc, 0.f) + log1pf(expf(-fabsf(sc)));  // softplus
                    float sd  = sp + 1e-4f;
                    float var = sd * sd;
                    zrow[k]   = fmaf(nv, sd, m);
                    kl_local += m * m + var - logf(var) - 1.0f;
                }
#pragma unroll
                for (int db = 0; db < 2; ++db) {
                    unsigned w[3][2];
#pragma unroll
                    for (int half = 0; half < 2; ++half) {
                        float x0 = zrow[db * 4 + half * 2], x1 = zrow[db * 4 + half * 2 + 1];
                        unsigned short a0 = f2bf(x0); float r1 = x0 - bf2f(a0);
                        unsigned short a1 = f2bf(r1); float r2 = r1 - bf2f(a1);
                        unsigned short a2 = f2bf(r2);
                        unsigned short b0 = f2bf(x1); float s1v = x1 - bf2f(b0);
                        unsigned short b1 = f2bf(s1v); float s2v = s1v - bf2f(b1);
                        unsigned short b2 = f2bf(s2v);
                        w[0][half] = (unsigned)a0 | ((unsigned)b0 << 16);
                        w[1][half] = (unsigned)a1 | ((unsigned)b1 << 16);
                        w[2][half] = (unsigned)a2 | ((unsigned)b2 << 16);
                    }
#pragma unroll
                    for (int tt = 0; tt < 3; ++tt)
                        zs[(tt * 16 + su * 2 + db) * 64 + c] = make_uint2(w[tt][0], w[tt][1]);
                }
            }
            __syncthreads();
            // ---- consume: wave su -> N-tile (su&3), mt range [mtbase, +nmt) ----
            {
                const int colB = (su & 3) * 16 + nl;
#pragma unroll
                for (int p = 0; p < 6; ++p) {
#pragma unroll
                    for (int kq = 0; kq < 2; ++kq) {
                        uint2 blo = zs[(PAIR_B[p] * 16 + kq * 8 + h) * 64 + colB];
                        uint2 bhi = zs[(PAIR_B[p] * 16 + kq * 8 + 4 + h) * 64 + colB];
                        uint4 bu = make_uint4(blo.x, blo.y, bhi.x, bhi.y);
                        bf16x8 bfr = *reinterpret_cast<bf16x8*>(&bu);
                        const uint4* Aw = reinterpret_cast<const uint4*>(afw)
                                          + (size_t)(((P * 6 + p) * 2 + kq) * 5) * 64 + l;
#pragma unroll
                        for (int q = 0; q < 3; ++q) {
                            if (q < nmt) {
                                uint4 au = Aw[(size_t)(mtbase + q) * 64];
                                bf16x8 af = *reinterpret_cast<bf16x8*>(&au);
                                acc[q] = __builtin_amdgcn_mfma_f32_16x16x32_bf16(af, bfr, acc[q], 0, 0, 0);
                            }
                        }
                    }
                }
            }
            __syncthreads();   // zs consumed (next produce / Zl overlays safe)
        }
        // ---- Zl store (rows < 72 ONLY: Zl region is exactly 72 rows) ------
#pragma unroll
        for (int q = 0; q < 3; ++q) {
            if (q < nmt) {
                const int row0 = (mtbase + q) * 16 + h * 4;
                if (row0 < 72) {
#pragma unroll
                    for (int r = 0; r < 4; ++r)
                        Zl[(row0 + r) * ZLS + (su & 3) * 16 + nl] = acc[q][r];
                }
            }
        }
    }

    float loss_local = 0.f;
    const int tg = su >> 2;        // tile group: waves 0-3 -> tile A, 4-7 -> tile B
    const int sv = su & 3;         // wave index within tile group

    // ================= RVQ loop over 9 codebooks ===========================
    for (int i = 0; i < NCB; ++i) {
        __syncthreads();  // Zl rows current (corrections of i-1 + phase-Z stores done)

        // ---- split: waves 0-1 handle 128 columns (tile = tid>>6) ----------
        if (tid < 128) {
            float*    Zl = (tid & 64) ? ZlB : ZlA;
            unsigned* es = (tid & 64) ? esB : esA;
            const int cc = tid & 63;
            float v[CD]; float n2 = 0.f;
#pragma unroll
            for (int j = 0; j < CD; ++j) { v[j] = Zl[(i * CD + j) * ZLS + cc]; n2 = fmaf(v[j], v[j], n2); }
            float inv = 1.0f / fmaxf(sqrtf(n2), 1e-12f);
            unsigned pk[3][4];
#pragma unroll
            for (int w = 0; w < 4; ++w) {
                float x0 = v[2 * w] * inv, x1 = v[2 * w + 1] * inv;
                unsigned short a0 = f2bf(x0); float r0 = x0 - bf2f(a0);
                unsigned short a1 = f2bf(r0); float q0 = r0 - bf2f(a1);
                unsigned short a2 = f2bf(q0);
                unsigned short b0 = f2bf(x1); float r1 = x1 - bf2f(b0);
                unsigned short b1 = f2bf(r1); float q1 = r1 - bf2f(b1);
                unsigned short b2 = f2bf(q1);
                pk[0][w] = (unsigned)a0 | ((unsigned)b0 << 16);
                pk[1][w] = (unsigned)a1 | ((unsigned)b1 << 16);
                pk[2][w] = (unsigned)a2 | ((unsigned)b2 << 16);
            }
            uint4* ep = reinterpret_cast<uint4*>(&es[(size_t)cc * 12]);
            ep[0] = make_uint4(pk[0][0], pk[0][1], pk[0][2], pk[0][3]);
            ep[1] = make_uint4(pk[1][0], pk[1][1], pk[1][2], pk[1][3]);
            ep[2] = make_uint4(pk[2][0], pk[2][1], pk[2][2], pk[2][3]);
        }
        // ---- latents: wave su writes z_e row su for both tiles ------------
        {
            float la0 = ZlA[(i * CD + su) * ZLS + c];
            float la1 = ZlB[(i * CD + su) * ZLS + c];
            o_lat[(size_t)b * (NCB * CD) * T + (size_t)(i * CD + su) * T + t0 + c]      = la0;
            o_lat[(size_t)b * (NCB * CD) * T + (size_t)(i * CD + su) * T + t0 + 64 + c] = la1;
        }
        __syncthreads();

        // ---- build B fragments for both tiles -----------------------------
        bf16x8 bfA[4][2], bfB[4][2];
        {
            const int dwo = (h & 1) * 2;
            const int tA  = h >> 1;
            const int tB  = 1 + (h >> 1);
#pragma unroll
            for (int pt = 0; pt < 4; ++pt) {
                const int col = pt * 16 + nl;
                {
                    uint2 lo0 = *reinterpret_cast<const uint2*>(&esA[col * 12 + 0 * 4 + dwo]);
                    uint2 hi0 = *reinterpret_cast<const uint2*>(&esA[col * 12 + tA * 4 + dwo]);
                    uint2 lh1 = *reinterpret_cast<const uint2*>(&esA[col * 12 + tB * 4 + dwo]);
                    uint4 t0v = make_uint4(lo0.x, lo0.y, hi0.x, hi0.y);
                    uint4 t1v = make_uint4(lh1.x, lh1.y, lh1.x, lh1.y);
                    bfA[pt][0] = *reinterpret_cast<bf16x8*>(&t0v);
                    bfA[pt][1] = *reinterpret_cast<bf16x8*>(&t1v);
                }
                {
                    uint2 lo0 = *reinterpret_cast<const uint2*>(&esB[col * 12 + 0 * 4 + dwo]);
                    uint2 hi0 = *reinterpret_cast<const uint2*>(&esB[col * 12 + tA * 4 + dwo]);
                    uint2 lh1 = *reinterpret_cast<const uint2*>(&esB[col * 12 + tB * 4 + dwo]);
                    uint4 t0v = make_uint4(lo0.x, lo0.y, hi0.x, hi0.y);
                    uint4 t1v = make_uint4(lh1.x, lh1.y, lh1.x, lh1.y);
                    bfB[pt][0] = *reinterpret_cast<bf16x8*>(&t0v);
                    bfB[pt][1] = *reinterpret_cast<bf16x8*>(&t1v);
                }
            }
        }

        // ---- MFMA search, both tiles: wave su owns entries [su*128, +128) --
        float bestA[4] = {-3.0e38f, -3.0e38f, -3.0e38f, -3.0e38f};
        float bestB[4] = {-3.0e38f, -3.0e38f, -3.0e38f, -3.0e38f};
        int   bidxA[4] = {0, 0, 0, 0};
        int   bidxB[4] = {0, 0, 0, 0};
        {
            const uint4* Ab = reinterpret_cast<const uint4*>(afr)
                              + ((size_t)(i * 64 + su * 8) * 2) * 64 + l;
            const f32x4* Hb = reinterpret_cast<const f32x4*>(h2c)
                              + (size_t)i * 256 + su * 32;
            int eb = su * 128 + h * 4;
#pragma unroll 2
            for (int e8 = 0; e8 < 8; ++e8) {
                uint4 ua0 = Ab[0];     // codebook fragments: loaded ONCE, feed both tiles
                uint4 ua1 = Ab[64];
                f32x4 hv  = Hb[e8 * 4 + h];
                bf16x8 a0 = *reinterpret_cast<bf16x8*>(&ua0);
                bf16x8 a1 = *reinterpret_cast<bf16x8*>(&ua1);
#pragma unroll
                for (int pt = 0; pt < 4; ++pt) {
                    f32x4 acA = __builtin_amdgcn_mfma_f32_16x16x32_bf16(a0, bfA[pt][0], hv, 0, 0, 0);
                    acA = __builtin_amdgcn_mfma_f32_16x16x32_bf16(a1, bfA[pt][1], acA, 0, 0, 0);
                    f32x4 acB = __builtin_amdgcn_mfma_f32_16x16x32_bf16(a0, bfB[pt][0], hv, 0, 0, 0);
                    acB = __builtin_amdgcn_mfma_f32_16x16x32_bf16(a1, bfB[pt][1], acB, 0, 0, 0);
#pragma unroll
                    for (int r = 0; r < 4; ++r) {
                        float sa = acA[r];
                        if (sa > bestA[pt]) { bestA[pt] = sa; bidxA[pt] = eb + r; }  // strict >: first idx
                        float sb = acB[r];
                        if (sb > bestB[pt]) { bestB[pt] = sb; bidxB[pt] = eb + r; }
                    }
                }
                Ab += 128; eb += 16;
            }
        }

        // wave-internal merge (explicit first-index tie-break), both tiles
#pragma unroll
        for (int off = 16; off <= 32; off <<= 1) {
#pragma unroll
            for (int pt = 0; pt < 4; ++pt) {
                float oa2 = __shfl_xor(bestA[pt], off, 64);
                int   oi  = __shfl_xor(bidxA[pt], off, 64);
                bool tk = (oa2 > bestA[pt]) || (oa2 == bestA[pt] && oi < bidxA[pt]);
                if (tk) { bestA[pt] = oa2; bidxA[pt] = oi; }
                float ob2 = __shfl_xor(bestB[pt], off, 64);
                int   oj  = __shfl_xor(bidxB[pt], off, 64);
                bool tk2 = (ob2 > bestB[pt]) || (ob2 == bestB[pt] && oj < bidxB[pt]);
                if (tk2) { bestB[pt] = ob2; bidxB[pt] = oj; }
            }
        }
        // lanes 0-15 write tile A; lanes 16-31 write tile B (merged copies equal)
        if (l < 16) {
#pragma unroll
            for (int pt = 0; pt < 4; ++pt) {
                redS[(0 * 8 + su) * 64 + pt * 16 + l] = bestA[pt];
                redI[(0 * 8 + su) * 64 + pt * 16 + l] = bidxA[pt];
            }
        } else if (l < 32) {
#pragma unroll
            for (int pt = 0; pt < 4; ++pt) {
                redS[(1 * 8 + su) * 64 + pt * 16 + (l - 16)] = bestB[pt];
                redI[(1 * 8 + su) * 64 + pt * 16 + (l - 16)] = bidxB[pt];
            }
        }
        __syncthreads();

        // final reduce: tile group tg, column c (ascending wave = ascending entries)
        float bsc = redS[(tg * 8) * 64 + c];
        int   bi  = redI[(tg * 8) * 64 + c];
#pragma unroll
        for (int ww = 1; ww < NW; ++ww) {
            float v2 = redS[(tg * 8 + ww) * 64 + c];
            int   vi = redI[(tg * 8 + ww) * 64 + c];
            if (v2 > bsc) { bsc = v2; bi = vi; }
        }
        cidx[(tg * NCB + i) * 64 + c] = bi;   // benign multi-write of identical value
        if (su == 0) o_codes[(size_t)b * NCB * T + (size_t)i * T + t0 + c]      = (float)bi;
        if (su == 4) o_codes[(size_t)b * NCB * T + (size_t)i * T + t0 + 64 + c] = (float)bi;

        // gather raw codebook row (per tile group); loss (once per column per tile)
        float cv[CD];
        {
            const float4* cr4 = (const float4*)(codebook + ((size_t)i * CB + bi) * CD);
            float4 qa = cr4[0], qb = cr4[1];
            cv[0] = qa.x; cv[1] = qa.y; cv[2] = qa.z; cv[3] = qa.w;
            cv[4] = qb.x; cv[5] = qb.y; cv[6] = qb.z; cv[7] = qb.w;
            if (su == 0 || su == 4) {
                float* Zl = tg ? ZlB : ZlA;
#pragma unroll
                for (int j = 0; j < CD; ++j) {
                    float dd = cv[j] - Zl[(i * CD + j) * ZLS + c];
                    loss_local = fmaf(dd, dd, loss_local);
                }
            }
        }

        // ---- corrections: tile group tg, rows (i+1)*8 .. 71, wave-strided --
        {
            float* Zl = tg ? ZlB : ZlA;
            const int nf = 64 - 8 * i;
            for (int rr = sv; rr < nf; rr += 4) {
                const int row = (i + 1) * 8 + rr;
                float zv = Zl[row * ZLS + c];
                const float* cm = CMt + ((size_t)i * 72 + row) * CD;
#pragma unroll
                for (int d2 = 0; d2 < CD; ++d2) zv = fmaf(-cm[d2], cv[d2], zv);
                Zl[row * ZLS + c] = zv;
            }
        }
    }
    __syncthreads();  // cidx complete

    // ================= final: z_q = obs + sum_i OP[i][code_i] ==============
    // waves 0-3: tile A rows sv*32..+31; waves 4-7: tile B
    {
        f32x4 oa[8];
#pragma unroll
        for (int kb = 0; kb < 8; ++kb)
            oa[kb] = *reinterpret_cast<const f32x4*>(obs + sv * 32 + kb * 4);
#pragma unroll
        for (int i2 = 0; i2 < NCB; ++i2) {
            int code = cidx[(tg * NCB + i2) * 64 + c];
            const f32x4* op = reinterpret_cast<const f32x4*>(OPt + ((size_t)(i2 * CB + code)) * D + sv * 32);
#pragma unroll
            for (int kb = 0; kb < 8; ++kb) oa[kb] += op[kb];
        }
        float* oq = o_zq + (size_t)b * D * T + (size_t)(sv * 32) * T + t0 + tg * 64 + c;
#pragma unroll
        for (int kb = 0; kb < 8; ++kb)
#pragma unroll
            for (int r = 0; r < 4; ++r)
                oq[(size_t)(kb * 4 + r) * T] = oa[kb][r];
    }

    // ================= scalar reductions ===================================
    float v = kl_local;
#pragma unroll
    for (int o = 32; o > 0; o >>= 1) v += __shfl_down(v, o, 64);
    float w2 = loss_local;
#pragma unroll
    for (int o = 32; o > 0; o >>= 1) w2 += __shfl_down(w2, o, 64);
    if ((tid & 63) == 0) { redw[s] = v; redw[NW + s] = w2; }
    __syncthreads();
    if (tid == 0) {
        float ks = 0.f, ls = 0.f;
#pragma unroll
        for (int q = 0; q < NW; ++q) { ks += redw[q]; ls += redw[NW + q]; }
        atomicAdd(&o_scal[0], ks * (1.0f / 65536.0f));               // kl: /(B*T)
        float lsn = ls * (1.0f / (524288.0f * 9.0f));                // /(B*8*T)/NCB
        atomicAdd(&o_scal[1], lsn);                                  // commitment
        atomicAdd(&o_scal[2], lsn);                                  // codebook (identical in eval)
    }
}

extern "C" void kernel_launch(void* const* d_in, const int* in_sizes, int n_in,
                              void* d_out, int out_size, void* d_ws, size_t ws_size,
                              hipStream_t stream) {
    const float* x        = (const float*)d_in[0];
    const float* noise    = (const float*)d_in[1];
    const float* in_w     = (const float*)d_in[2];
    const float* in_b     = (const float*)d_in[3];
    const float* codebook = (const float*)d_in[4];
    const float* out_w    = (const float*)d_in[5];
    const float* out_b    = (const float*)d_in[6];

    float* out     = (float*)d_out;
    float* o_zq    = out + OFF_ZQ;
    float* o_scal  = out + OFF_SCAL;
    float* o_codes = out + OFF_CODES;
    float* o_lat   = out + OFF_LAT;

    unsigned* afr = (unsigned*)d_ws;
    float*    h2c = (float*)(afr + AFR_U32);
    unsigned* afw = (unsigned*)(h2c + H2C_F32);
    float*    CMt = (float*)(afw + AFW_U32);
    float*    obs = CMt + CM_F32;
    float*    bef = obs + OBS_F32;
    float*    OPt = bef + BEF_F32;

    const int prep_total = 2 * NCB * CB + NCB * 72 + 128 + 72 + 7680;  // 26960
    prep_kernel<<<(prep_total + 255) / 256, 256, 0, stream>>>(
        codebook, in_w, in_b, out_w, out_b, afr, h2c, afw, CMt, obs, bef, OPt, o_scal);

    dim3 grid(BB * (T / (TBLK * 2)));  // 16 * 32 = 512 blocks, 2 tiles each
    rvq_kernel<<<grid, NTHR, 0, stream>>>(x, noise, codebook,
                                          afr, h2c, afw, CMt, obs, bef, OPt,
                                          o_zq, o_scal, o_codes, o_lat);
}